// Round 13
// baseline (334.889 us; speedup 1.0000x reference)
//
#include <hip/hip_runtime.h>
#include <math.h>

#define NN 50000
#define NE 800000
#define HID 128
#define NL 3
#define NG 64
#define LAT 64

typedef __attribute__((ext_vector_type(8))) short short8v;
typedef __attribute__((ext_vector_type(4))) short short4v;
typedef __attribute__((ext_vector_type(4))) float f32x4;
typedef __attribute__((ext_vector_type(2))) float f32x2;

__device__ __forceinline__ float bf2f(unsigned short b) {
    unsigned u = ((unsigned)b) << 16;
    return __builtin_bit_cast(float, u);
}
__device__ __forceinline__ unsigned short f2bf(float f) {
    unsigned u = __builtin_bit_cast(unsigned, f);
    u += 0x7FFFu + ((u >> 16) & 1u);   // round-to-nearest-even
    return (unsigned short)(u >> 16);
}

// decode 8 fp8 e4m3 (two dwords) against qf[8]: dot product
__device__ __forceinline__ float dot8_fp8(int d0, int d1, const float* qf) {
    f32x2 a01 = __builtin_amdgcn_cvt_pk_f32_fp8(d0, false);
    f32x2 a23 = __builtin_amdgcn_cvt_pk_f32_fp8(d0, true);
    f32x2 a45 = __builtin_amdgcn_cvt_pk_f32_fp8(d1, false);
    f32x2 a67 = __builtin_amdgcn_cvt_pk_f32_fp8(d1, true);
    return a01[0]*qf[0] + a01[1]*qf[1] + a23[0]*qf[2] + a23[1]*qf[3]
         + a45[0]*qf[4] + a45[1]*qf[5] + a67[0]*qf[6] + a67[1]*qf[7];
}
// decode 8 fp8 e4m3 (two dwords), acc += wgt * v
__device__ __forceinline__ void acc8_fp8(int d0, int d1, float wgt, float* acc) {
    f32x2 v01 = __builtin_amdgcn_cvt_pk_f32_fp8(d0, false);
    f32x2 v23 = __builtin_amdgcn_cvt_pk_f32_fp8(d0, true);
    f32x2 v45 = __builtin_amdgcn_cvt_pk_f32_fp8(d1, false);
    f32x2 v67 = __builtin_amdgcn_cvt_pk_f32_fp8(d1, true);
    acc[0] += wgt * v01[0]; acc[1] += wgt * v01[1];
    acc[2] += wgt * v23[0]; acc[3] += wgt * v23[1];
    acc[4] += wgt * v45[0]; acc[5] += wgt * v45[1];
    acc[6] += wgt * v67[0]; acc[7] += wgt * v67[1];
}

// ---------------- pack: transpose all W to [kb][col][8] bf16 + zero-init ----
// Layer Wt: Wt[((l*16 + kb)*512 + c)*8 + i] = W_m[j][kb*8+i], m=c>>7, j=c&127.
// Input Wt0: Wt0[(kb*128 + j)*8 + i] = Win[j][kb*8+i].
struct PtrTab { const float* p[13]; };

__global__ __launch_bounds__(256) void pack_all_kernel(
    PtrTab wt, PtrTab bt, short* __restrict__ Wt0, short* __restrict__ Wt,
    float* __restrict__ bcat, int* __restrict__ deg, float* __restrict__ pooled)
{
    int gid = blockIdx.x * 256 + threadIdx.x;          // grid covers 12*16384
    if (gid < 16384) {                                 // input Win, transposed
        int i  = gid & 7;
        int j  = (gid >> 3) & 127;
        int kb = gid >> 10;
        Wt0[gid] = (short)f2bf(wt.p[0][j * 128 + kb * 8 + i]);
    }
    if (gid < 12 * 16384) {                            // layer W, transposed
        int i  = gid & 7;
        int c  = (gid >> 3) & 511;
        int kb = (gid >> 12) & 15;
        int l  = gid >> 16;
        int slot = 1 + 4 * l + (c >> 7);
        int elem = (c & 127) * 128 + kb * 8 + i;
        Wt[gid] = (short)f2bf(wt.p[slot][elem]);
    }
    if (gid < 13 * 128) {
        int slot = gid >> 7, e = gid & 127;
        bcat[gid] = bt.p[slot][e];
    }
    if (gid < NN) deg[gid] = 0;
    if (gid < NG * HID) pooled[gid] = 0.f;
}

// ---------------- layer GEMM: barrier-free, W direct from L2 (R12-proven) --
__global__ __launch_bounds__(512) void gemm_layer(
    const short* __restrict__ A, const short* __restrict__ Wt_l,
    const float* __restrict__ bias, short* __restrict__ qs,
    signed char* __restrict__ kv8, int nrows)
{
    constexpr int CSTR = 516;
    __shared__ short Clds[16 * CSTR];      // 16.5KB

    const int tid  = threadIdx.x;
    const int lane = tid & 63;
    const int wid  = tid >> 6;             // 0..7 -> col group
    const int n0   = wid * 64;
    const int lg   = lane >> 4;
    const int l15  = lane & 15;
    const int rb   = blockIdx.x * 64;
    const int r0   = rb + l15;

    f32x4 acc[4][4];
#pragma unroll
    for (int i = 0; i < 4; ++i)
#pragma unroll
        for (int j = 0; j < 4; ++j) acc[i][j] = {0.f, 0.f, 0.f, 0.f};

    const short8v zero8 = {0, 0, 0, 0, 0, 0, 0, 0};

#pragma unroll
    for (int s = 0; s < 4; ++s) {
        short8v a[4], b[4];
#pragma unroll
        for (int mf = 0; mf < 4; ++mf) {
            int row = r0 + mf * 16;
            a[mf] = (row < nrows)
                ? *reinterpret_cast<const short8v*>(&A[(size_t)row * HID + s * 32 + lg * 8])
                : zero8;
        }
        const int kb = s * 4 + lg;
#pragma unroll
        for (int nf = 0; nf < 4; ++nf) {
            int col = n0 + nf * 16 + l15;
            b[nf] = *reinterpret_cast<const short8v*>(&Wt_l[((size_t)kb * 512 + col) * 8]);
        }
#pragma unroll
        for (int mf = 0; mf < 4; ++mf)
#pragma unroll
            for (int nf = 0; nf < 4; ++nf)
                acc[mf][nf] = __builtin_amdgcn_mfma_f32_16x16x32_bf16(
                    a[mf], b[nf], acc[mf][nf], 0, 0, 0);
    }

    // ---- epilogue: 4 passes of 16 rows through LDS ----
#pragma unroll
    for (int mf = 0; mf < 4; ++mf) {
        __syncthreads();
#pragma unroll
        for (int nf = 0; nf < 4; ++nf) {
            int col = n0 + nf * 16 + l15;
            float bv = bias[col];
#pragma unroll
            for (int qq = 0; qq < 4; ++qq) {
                int rl = lg * 4 + qq;              // 0..15
                Clds[rl * CSTR + col] = (short)f2bf(acc[mf][nf][qq] + bv);
            }
        }
        __syncthreads();
#pragma unroll
        for (int i = 0; i < 2; ++i) {              // 16 rows * 64 chunks / 512
            int c = tid + 512 * i;
            int rl = c >> 6;
            int ck = c & 63;
            int grow = rb + mf * 16 + rl;
            if (grow < nrows) {
                if (ck < 16) {                     // Q -> qs (stride 256)
                    *reinterpret_cast<short8v*>(&qs[(size_t)grow * 256 + ck * 8]) =
                        *reinterpret_cast<const short8v*>(&Clds[rl * CSTR + ck * 8]);
                } else if (ck < 48) {              // K/V -> fp8 interleaved
                    short8v cv = *reinterpret_cast<const short8v*>(&Clds[rl * CSTR + ck * 8]);
                    float f0 = bf2f((unsigned short)cv[0]), f1 = bf2f((unsigned short)cv[1]);
                    float f2 = bf2f((unsigned short)cv[2]), f3 = bf2f((unsigned short)cv[3]);
                    float f4 = bf2f((unsigned short)cv[4]), f5 = bf2f((unsigned short)cv[5]);
                    float f6 = bf2f((unsigned short)cv[6]), f7 = bf2f((unsigned short)cv[7]);
                    int w0 = __builtin_amdgcn_cvt_pk_fp8_f32(f0, f1, 0, false);
                    w0     = __builtin_amdgcn_cvt_pk_fp8_f32(f2, f3, w0, true);
                    int w1 = __builtin_amdgcn_cvt_pk_fp8_f32(f4, f5, 0, false);
                    w1     = __builtin_amdgcn_cvt_pk_fp8_f32(f6, f7, w1, true);
                    int off = (ck < 32) ? (ck - 16) * 16 : ((ck - 32) * 16 + 8);
                    *reinterpret_cast<int2*>(kv8 + (size_t)grow * 256 + off) =
                        make_int2(w0, w1);
                } else {                           // skip -> qs at +128
                    *reinterpret_cast<short8v*>(&qs[(size_t)grow * 256 + 128 + (ck - 48) * 8]) =
                        *reinterpret_cast<const short8v*>(&Clds[rl * CSTR + ck * 8]);
                }
            }
        }
    }
}

// ---------------- input GEMM: barrier-free, W direct from L2 ---------------
// Block = 64 rows x 128 cols, 128 thr = 2 waves, wave tile 64x64. 782 blocks
// (fixes 196-block grid quantization). fp32 A converted on load.
__global__ __launch_bounds__(128) void gemm_in(
    const float* __restrict__ Af, const short* __restrict__ Wt0,
    const float* __restrict__ bias, short* __restrict__ out, int nrows)
{
    constexpr int CSTR = 132;
    __shared__ short Clds[16 * CSTR];      // 4.2KB

    const int tid  = threadIdx.x;
    const int lane = tid & 63;
    const int wid  = tid >> 6;             // 0..1 -> col half
    const int n0   = wid * 64;
    const int lg   = lane >> 4;
    const int l15  = lane & 15;
    const int rb   = blockIdx.x * 64;
    const int r0   = rb + l15;

    f32x4 acc[4][4];
#pragma unroll
    for (int i = 0; i < 4; ++i)
#pragma unroll
        for (int j = 0; j < 4; ++j) acc[i][j] = {0.f, 0.f, 0.f, 0.f};

    const short8v zero8 = {0, 0, 0, 0, 0, 0, 0, 0};

#pragma unroll
    for (int s = 0; s < 4; ++s) {
        short8v a[4], b[4];
#pragma unroll
        for (int mf = 0; mf < 4; ++mf) {
            int row = r0 + mf * 16;
            if (row < nrows) {
                const float* ap = Af + (size_t)row * HID + s * 32 + lg * 8;
                float4 f0 = *reinterpret_cast<const float4*>(ap);
                float4 f1 = *reinterpret_cast<const float4*>(ap + 4);
                short8v t;
                t[0] = (short)f2bf(f0.x); t[1] = (short)f2bf(f0.y);
                t[2] = (short)f2bf(f0.z); t[3] = (short)f2bf(f0.w);
                t[4] = (short)f2bf(f1.x); t[5] = (short)f2bf(f1.y);
                t[6] = (short)f2bf(f1.z); t[7] = (short)f2bf(f1.w);
                a[mf] = t;
            } else a[mf] = zero8;
        }
        const int kb = s * 4 + lg;
#pragma unroll
        for (int nf = 0; nf < 4; ++nf) {
            int col = n0 + nf * 16 + l15;
            b[nf] = *reinterpret_cast<const short8v*>(&Wt0[((size_t)kb * 128 + col) * 8]);
        }
#pragma unroll
        for (int mf = 0; mf < 4; ++mf)
#pragma unroll
            for (int nf = 0; nf < 4; ++nf)
                acc[mf][nf] = __builtin_amdgcn_mfma_f32_16x16x32_bf16(
                    a[mf], b[nf], acc[mf][nf], 0, 0, 0);
    }

#pragma unroll
    for (int mf = 0; mf < 4; ++mf) {
        __syncthreads();
#pragma unroll
        for (int nf = 0; nf < 4; ++nf) {
            int col = n0 + nf * 16 + l15;
            float bv = bias[col];
#pragma unroll
            for (int qq = 0; qq < 4; ++qq) {
                int rl = lg * 4 + qq;              // 0..15
                Clds[rl * CSTR + col] = (short)f2bf(acc[mf][nf][qq] + bv);
            }
        }
        __syncthreads();
#pragma unroll
        for (int i = 0; i < 2; ++i) {              // 16 rows * 16 chunks / 128
            int c = tid + 128 * i;
            int rl = c >> 4;
            int ck = c & 15;
            int grow = rb + mf * 16 + rl;
            if (grow < nrows)
                *reinterpret_cast<short8v*>(&out[(size_t)grow * HID + ck * 8]) =
                    *reinterpret_cast<const short8v*>(&Clds[rl * CSTR + ck * 8]);
        }
    }
}

// ---------------- CSR build ----------------
__global__ __launch_bounds__(256) void count_deg_kernel(
    const int* __restrict__ dst, int* __restrict__ deg,
    unsigned short* __restrict__ rank16, int ne)
{
    int e = blockIdx.x * 256 + threadIdx.x;
    if (e < ne) {
        int r = atomicAdd(&deg[dst[e]], 1);
        rank16[e] = (unsigned short)r;
    }
}

__global__ __launch_bounds__(1024) void scan1_kernel(
    const int* __restrict__ deg, int* __restrict__ offsets,
    int* __restrict__ bsum, int n)
{
    __shared__ int wsum[16];
    const int tid = threadIdx.x, wid = tid >> 6, lane = tid & 63;
    int i = blockIdx.x * 1024 + tid;
    int val = (i < n) ? deg[i] : 0;
    int x = val;
#pragma unroll
    for (int off = 1; off < 64; off <<= 1) {
        int y = __shfl_up(x, off);
        if (lane >= off) x += y;
    }
    if (lane == 63) wsum[wid] = x;
    __syncthreads();
    if (tid < 16) {
        int w = wsum[tid];
#pragma unroll
        for (int off = 1; off < 16; off <<= 1) {
            int y = __shfl_up(w, off);
            if (tid >= off) w += y;
        }
        wsum[tid] = w;
    }
    __syncthreads();
    int incl = x + (wid ? wsum[wid - 1] : 0);
    if (i < n) offsets[i + 1] = incl;
    if (tid == 1023) bsum[blockIdx.x] = incl;
}

__global__ __launch_bounds__(256) void scan3_kernel(
    int* __restrict__ offsets, const int* __restrict__ bsum, int n, int nb)
{
    __shared__ int sx[64];
    const int tid = threadIdx.x;
    if (tid < 64) {
        int vv = (tid < nb) ? bsum[tid] : 0;
        int x = vv;
#pragma unroll
        for (int off = 1; off < 64; off <<= 1) {
            int y = __shfl_up(x, off);
            if (tid >= off) x += y;
        }
        sx[tid] = x - vv;   // exclusive prefix of block sums
    }
    __syncthreads();
    int i = blockIdx.x * 256 + tid;
    if (i >= n) return;
    offsets[i + 1] += sx[i >> 10];
    if (i == 0) offsets[0] = 0;
}

__global__ __launch_bounds__(256) void scatter_kernel(
    const int* __restrict__ src, const int* __restrict__ dst,
    const int* __restrict__ offsets, const unsigned short* __restrict__ rank16,
    unsigned short* __restrict__ csr16, int ne)
{
    int e = blockIdx.x * 256 + threadIdx.x;
    if (e < ne) {
        int pos = offsets[dst[e]] + rank16[e];
        csr16[pos] = (unsigned short)src[e];
    }
}

// ---------------- fused attention + skip + ReLU ----------------
__global__ __launch_bounds__(256) void attn_kernel(
    const short* __restrict__ qs, const signed char* __restrict__ kv8,
    const int* __restrict__ offsets, const unsigned short* __restrict__ csr16,
    short* __restrict__ hout, int nnodes)
{
    int node = (blockIdx.x * 256 + threadIdx.x) >> 6;
    if (node >= nnodes) return;
    const int lane = threadIdx.x & 63;
    const int grp = lane >> 4;        // edge slot 0..3
    const int g   = lane & 15;        // dims 8g..8g+7 (head = g/4)
    const float scale = 0.17677669529663687f; // 1/sqrt(32)

    const size_t nb = (size_t)node * 256;
    short8v q8 = *reinterpret_cast<const short8v*>(&qs[nb + g * 8]);
    float qf[8];
#pragma unroll
    for (int i = 0; i < 8; ++i) qf[i] = bf2f((unsigned short)q8[i]);

    int e0 = offsets[node], e1 = offsets[node + 1];
    float s = 0.f;
    float acc[8] = {0.f, 0.f, 0.f, 0.f, 0.f, 0.f, 0.f, 0.f};

    const signed char* kvb = kv8 + g * 16;

    int e = e0 + grp;
    int i0 = (e < e1)     ? (int)csr16[e]     : 0;
    int i1 = (e + 4 < e1) ? (int)csr16[e + 4] : 0;

    for (; e + 4 < e1; e += 8) {
        int j0 = (e + 8  < e1) ? (int)csr16[e + 8]  : 0;   // prefetch next pair
        int j1 = (e + 12 < e1) ? (int)csr16[e + 12] : 0;
        int4 kv0 = *reinterpret_cast<const int4*>(kvb + ((size_t)i0 << 8));
        int4 kv1 = *reinterpret_cast<const int4*>(kvb + ((size_t)i1 << 8));
        float p0 = dot8_fp8(kv0.x, kv0.y, qf);
        float p1 = dot8_fp8(kv1.x, kv1.y, qf);
        p0 += __shfl_xor(p0, 1);  p1 += __shfl_xor(p1, 1);
        p0 += __shfl_xor(p0, 2);  p1 += __shfl_xor(p1, 2);
        float w0 = __expf(fminf(p0 * scale, 60.f));
        float w1 = __expf(fminf(p1 * scale, 60.f));
        s += w0 + w1;
        acc8_fp8(kv0.z, kv0.w, w0, acc);
        acc8_fp8(kv1.z, kv1.w, w1, acc);
        i0 = j0; i1 = j1;
    }
    if (e < e1) {
        int4 kv0 = *reinterpret_cast<const int4*>(kvb + ((size_t)i0 << 8));
        float p0 = dot8_fp8(kv0.x, kv0.y, qf);
        p0 += __shfl_xor(p0, 1);
        p0 += __shfl_xor(p0, 2);
        float w0 = __expf(fminf(p0 * scale, 60.f));
        s += w0;
        acc8_fp8(kv0.z, kv0.w, w0, acc);
    }

    // merge the 4 edge slots (once per node)
#pragma unroll
    for (int off = 16; off <= 32; off <<= 1) {
        s += __shfl_xor(s, off);
#pragma unroll
        for (int i = 0; i < 8; ++i) acc[i] += __shfl_xor(acc[i], off);
    }
    float inv = 1.f / (s + 1e-16f);
    short8v sk8 = *reinterpret_cast<const short8v*>(&qs[nb + 128 + g * 8]);
    short8v o;
#pragma unroll
    for (int i = 0; i < 8; ++i) {
        float ov = fmaxf(acc[i] * inv + bf2f((unsigned short)sk8[i]), 0.f);
        o[i] = (short)f2bf(ov);
    }
    *reinterpret_cast<short8v*>(&hout[(size_t)node * HID + g * 8]) = o;
}

// ---------------- pooling over sorted batch (bf16 h) ----------------
// 391 blocks x (16 row-streams x 16 col-groups), short8v loads.
__global__ __launch_bounds__(256) void pool_kernel(
    const short* __restrict__ h, const int* __restrict__ batch,
    float* __restrict__ pooled, int nnodes)
{
    const int ROWS = 128;
    int n0 = blockIdx.x * ROWS;
    if (n0 >= nnodes) return;
    int n1 = min(n0 + ROWS, nnodes);
    int rg = threadIdx.x >> 4;      // 16 parallel row streams
    int c8 = threadIdx.x & 15;      // 8 cols each (16B loads)
    float s[8] = {0.f, 0.f, 0.f, 0.f, 0.f, 0.f, 0.f, 0.f};
    int g = -1;
    for (int n = n0 + rg; n < n1; n += 16) {
        int bg = batch[n];
        if (bg != g) {
            if (g >= 0) {
#pragma unroll
                for (int i = 0; i < 8; ++i) {
                    atomicAdd(&pooled[g * HID + c8 * 8 + i], s[i]);
                    s[i] = 0.f;
                }
            }
            g = bg;
        }
        short8v hv = *reinterpret_cast<const short8v*>(&h[(size_t)n * HID + c8 * 8]);
#pragma unroll
        for (int i = 0; i < 8; ++i) s[i] += bf2f((unsigned short)hv[i]);
    }
    if (g >= 0) {
#pragma unroll
        for (int i = 0; i < 8; ++i)
            atomicAdd(&pooled[g * HID + c8 * 8 + i], s[i]);
    }
}

// ---------------- final FC ----------------
__global__ __launch_bounds__(256) void fc_kernel(
    const float* __restrict__ pooled, const float* __restrict__ Wfc,
    const float* __restrict__ bfc, float* __restrict__ out)
{
    int t = blockIdx.x * 256 + threadIdx.x;   // 4096 = G*LAT
    if (t >= NG * LAT) return;
    int g = t >> 6, o = t & 63;
    float sum = bfc[o];
    for (int j = 0; j < HID; j += 4) {
        float4 p = *reinterpret_cast<const float4*>(&pooled[g * HID + j]);
        float4 w = *reinterpret_cast<const float4*>(&Wfc[o * HID + j]);
        sum += p.x * w.x + p.y * w.y + p.z * w.z + p.w * w.w;
    }
    out[t] = sum;
}

extern "C" void kernel_launch(void* const* d_in, const int* in_sizes, int n_in,
                              void* d_out, int out_size, void* d_ws, size_t ws_size,
                              hipStream_t stream)
{
    const float* x     = (const float*)d_in[0];
    const int*   ei    = (const int*)d_in[1];
    const int*   batch = (const int*)d_in[2];
    const float* Win   = (const float*)d_in[3];
    const float* bin_  = (const float*)d_in[4];
    const float* Wq    = (const float*)d_in[5];
    const float* bq    = (const float*)d_in[6];
    const float* Wk    = (const float*)d_in[7];
    const float* bk    = (const float*)d_in[8];
    const float* Wv    = (const float*)d_in[9];
    const float* bv    = (const float*)d_in[10];
    const float* Wskip = (const float*)d_in[11];
    const float* bskip = (const float*)d_in[12];
    const float* Wfc   = (const float*)d_in[13];
    const float* bfc   = (const float*)d_in[14];
    float* out = (float*)d_out;

    // workspace layout (~57 MB), 256B-aligned chunks
    char* ws = (char*)d_ws;
    auto alloc = [&](size_t bytes) {
        void* p = (void*)ws;
        ws += (bytes + 255) & ~(size_t)255;
        return p;
    };
    short* hb     = (short*)alloc((size_t)NN * HID * 2);
    short* qs     = (short*)alloc((size_t)NN * 256 * 2);   // Q(128) + skip(128)
    signed char* kv8 = (signed char*)alloc((size_t)NN * 256); // fp8 K|V interleaved
    short* Wt0    = (short*)alloc((size_t)16384 * 2);      // input Win transposed
    short* Wt     = (short*)alloc((size_t)12 * 16384 * 2); // layer W transposed
    float* bcat   = (float*)alloc((size_t)13 * 128 * 4);
    float* pooled = (float*)alloc((size_t)NG * HID * 4);
    int* deg      = (int*)alloc((size_t)NN * 4);
    int* offsets  = (int*)alloc((size_t)(NN + 1) * 4);
    int* bsum     = (int*)alloc((size_t)64 * 4);
    unsigned short* rank16 = (unsigned short*)alloc((size_t)NE * 2);
    unsigned short* csr16  = (unsigned short*)alloc((size_t)NE * 2);

    const int* esrc = ei;
    const int* edst = ei + NE;

    PtrTab wt, bt;
    wt.p[0] = Win; bt.p[0] = bin_;
    for (int l = 0; l < NL; ++l) {
        wt.p[1 + 4 * l] = Wq    + (size_t)l * HID * HID;
        wt.p[2 + 4 * l] = Wk    + (size_t)l * HID * HID;
        wt.p[3 + 4 * l] = Wv    + (size_t)l * HID * HID;
        wt.p[4 + 4 * l] = Wskip + (size_t)l * HID * HID;
        bt.p[1 + 4 * l] = bq    + (size_t)l * HID;
        bt.p[2 + 4 * l] = bk    + (size_t)l * HID;
        bt.p[3 + 4 * l] = bv    + (size_t)l * HID;
        bt.p[4 + 4 * l] = bskip + (size_t)l * HID;
    }

    pack_all_kernel<<<(12 * 16384 + 255) / 256, 256, 0, stream>>>(
        wt, bt, Wt0, Wt, bcat, deg, pooled);

    const int egrid = (NE + 255) / 256;
    const int nsb = (NN + 1023) / 1024;   // 49
    count_deg_kernel<<<egrid, 256, 0, stream>>>(edst, deg, rank16, NE);
    scan1_kernel<<<nsb, 1024, 0, stream>>>(deg, offsets, bsum, NN);
    scan3_kernel<<<(NN + 255) / 256, 256, 0, stream>>>(offsets, bsum, NN, nsb);
    scatter_kernel<<<egrid, 256, 0, stream>>>(esrc, edst, offsets, rank16, csr16, NE);

    // input projection: h = x @ Win^T + bin (fp32 A converted on load)
    const int gl = (NN + 63) / 64;        // 782
    gemm_in<<<gl, 128, 0, stream>>>(x, Wt0, bcat, hb, NN);

    for (int l = 0; l < NL; ++l) {
        gemm_layer<<<gl, 512, 0, stream>>>(
            hb, Wt + (size_t)l * 16 * 512 * 8, bcat + (1 + 4 * l) * 128, qs, kv8, NN);
        attn_kernel<<<(NN + 3) / 4, 256, 0, stream>>>(qs, kv8, offsets, csr16, hb, NN);
    }

    pool_kernel<<<(NN + 127) / 128, 256, 0, stream>>>(hb, batch, pooled, NN);
    fc_kernel<<<16, 256, 0, stream>>>(pooled, Wfc, bfc, out);
}

// Round 14
// 286.499 us; speedup vs baseline: 1.1689x; 1.1689x over previous
//
#include <hip/hip_runtime.h>
#include <math.h>

#define NN 50000
#define NE 800000
#define HID 128
#define NL 3
#define NG 64
#define LAT 64

typedef __attribute__((ext_vector_type(8))) short short8v;
typedef __attribute__((ext_vector_type(4))) short short4v;
typedef __attribute__((ext_vector_type(4))) float f32x4;
typedef __attribute__((ext_vector_type(2))) float f32x2;

__device__ __forceinline__ float bf2f(unsigned short b) {
    unsigned u = ((unsigned)b) << 16;
    return __builtin_bit_cast(float, u);
}
__device__ __forceinline__ unsigned short f2bf(float f) {
    unsigned u = __builtin_bit_cast(unsigned, f);
    u += 0x7FFFu + ((u >> 16) & 1u);   // round-to-nearest-even
    return (unsigned short)(u >> 16);
}

// decode 8 fp8 e4m3 (two dwords) against qf[8]: dot product
__device__ __forceinline__ float dot8_fp8(int d0, int d1, const float* qf) {
    f32x2 a01 = __builtin_amdgcn_cvt_pk_f32_fp8(d0, false);
    f32x2 a23 = __builtin_amdgcn_cvt_pk_f32_fp8(d0, true);
    f32x2 a45 = __builtin_amdgcn_cvt_pk_f32_fp8(d1, false);
    f32x2 a67 = __builtin_amdgcn_cvt_pk_f32_fp8(d1, true);
    return a01[0]*qf[0] + a01[1]*qf[1] + a23[0]*qf[2] + a23[1]*qf[3]
         + a45[0]*qf[4] + a45[1]*qf[5] + a67[0]*qf[6] + a67[1]*qf[7];
}
// decode 8 fp8 e4m3 (two dwords), acc += wgt * v
__device__ __forceinline__ void acc8_fp8(int d0, int d1, float wgt, float* acc) {
    f32x2 v01 = __builtin_amdgcn_cvt_pk_f32_fp8(d0, false);
    f32x2 v23 = __builtin_amdgcn_cvt_pk_f32_fp8(d0, true);
    f32x2 v45 = __builtin_amdgcn_cvt_pk_f32_fp8(d1, false);
    f32x2 v67 = __builtin_amdgcn_cvt_pk_f32_fp8(d1, true);
    acc[0] += wgt * v01[0]; acc[1] += wgt * v01[1];
    acc[2] += wgt * v23[0]; acc[3] += wgt * v23[1];
    acc[4] += wgt * v45[0]; acc[5] += wgt * v45[1];
    acc[6] += wgt * v67[0]; acc[7] += wgt * v67[1];
}

// ---------------- pack: transpose all W to [kb][col][8] bf16 + zero-init ----
struct PtrTab { const float* p[13]; };

__global__ __launch_bounds__(256) void pack_all_kernel(
    PtrTab wt, PtrTab bt, short* __restrict__ Wt0, short* __restrict__ Wt,
    float* __restrict__ bcat, int* __restrict__ deg, float* __restrict__ pooled)
{
    int gid = blockIdx.x * 256 + threadIdx.x;          // grid covers 12*16384
    if (gid < 16384) {                                 // input Win, transposed
        int i  = gid & 7;
        int j  = (gid >> 3) & 127;
        int kb = gid >> 10;
        Wt0[gid] = (short)f2bf(wt.p[0][j * 128 + kb * 8 + i]);
    }
    if (gid < 12 * 16384) {                            // layer W, transposed
        int i  = gid & 7;
        int c  = (gid >> 3) & 511;
        int kb = (gid >> 12) & 15;
        int l  = gid >> 16;
        int slot = 1 + 4 * l + (c >> 7);
        int elem = (c & 127) * 128 + kb * 8 + i;
        Wt[gid] = (short)f2bf(wt.p[slot][elem]);
    }
    if (gid < 13 * 128) {
        int slot = gid >> 7, e = gid & 127;
        bcat[gid] = bt.p[slot][e];
    }
    if (gid < NN) deg[gid] = 0;
    if (gid < NG * HID) pooled[gid] = 0.f;
}

// ---------------- layer GEMM: barrier-free, W direct from L2 (R12-proven) --
__global__ __launch_bounds__(512) void gemm_layer(
    const short* __restrict__ A, const short* __restrict__ Wt_l,
    const float* __restrict__ bias, short* __restrict__ qs,
    signed char* __restrict__ kv8, int nrows)
{
    constexpr int CSTR = 516;
    __shared__ short Clds[16 * CSTR];      // 16.5KB

    const int tid  = threadIdx.x;
    const int lane = tid & 63;
    const int wid  = tid >> 6;             // 0..7 -> col group
    const int n0   = wid * 64;
    const int lg   = lane >> 4;
    const int l15  = lane & 15;
    const int rb   = blockIdx.x * 64;
    const int r0   = rb + l15;

    f32x4 acc[4][4];
#pragma unroll
    for (int i = 0; i < 4; ++i)
#pragma unroll
        for (int j = 0; j < 4; ++j) acc[i][j] = {0.f, 0.f, 0.f, 0.f};

    const short8v zero8 = {0, 0, 0, 0, 0, 0, 0, 0};

#pragma unroll
    for (int s = 0; s < 4; ++s) {
        short8v a[4], b[4];
#pragma unroll
        for (int mf = 0; mf < 4; ++mf) {
            int row = r0 + mf * 16;
            a[mf] = (row < nrows)
                ? *reinterpret_cast<const short8v*>(&A[(size_t)row * HID + s * 32 + lg * 8])
                : zero8;
        }
        const int kb = s * 4 + lg;
#pragma unroll
        for (int nf = 0; nf < 4; ++nf) {
            int col = n0 + nf * 16 + l15;
            b[nf] = *reinterpret_cast<const short8v*>(&Wt_l[((size_t)kb * 512 + col) * 8]);
        }
#pragma unroll
        for (int mf = 0; mf < 4; ++mf)
#pragma unroll
            for (int nf = 0; nf < 4; ++nf)
                acc[mf][nf] = __builtin_amdgcn_mfma_f32_16x16x32_bf16(
                    a[mf], b[nf], acc[mf][nf], 0, 0, 0);
    }

    // ---- epilogue: 4 passes of 16 rows through LDS ----
#pragma unroll
    for (int mf = 0; mf < 4; ++mf) {
        __syncthreads();
#pragma unroll
        for (int nf = 0; nf < 4; ++nf) {
            int col = n0 + nf * 16 + l15;
            float bv = bias[col];
#pragma unroll
            for (int qq = 0; qq < 4; ++qq) {
                int rl = lg * 4 + qq;              // 0..15
                Clds[rl * CSTR + col] = (short)f2bf(acc[mf][nf][qq] + bv);
            }
        }
        __syncthreads();
#pragma unroll
        for (int i = 0; i < 2; ++i) {              // 16 rows * 64 chunks / 512
            int c = tid + 512 * i;
            int rl = c >> 6;
            int ck = c & 63;
            int grow = rb + mf * 16 + rl;
            if (grow < nrows) {
                if (ck < 16) {                     // Q -> qs (stride 256)
                    *reinterpret_cast<short8v*>(&qs[(size_t)grow * 256 + ck * 8]) =
                        *reinterpret_cast<const short8v*>(&Clds[rl * CSTR + ck * 8]);
                } else if (ck < 48) {              // K/V -> fp8 interleaved
                    short8v cv = *reinterpret_cast<const short8v*>(&Clds[rl * CSTR + ck * 8]);
                    float f0 = bf2f((unsigned short)cv[0]), f1 = bf2f((unsigned short)cv[1]);
                    float f2 = bf2f((unsigned short)cv[2]), f3 = bf2f((unsigned short)cv[3]);
                    float f4 = bf2f((unsigned short)cv[4]), f5 = bf2f((unsigned short)cv[5]);
                    float f6 = bf2f((unsigned short)cv[6]), f7 = bf2f((unsigned short)cv[7]);
                    int w0 = __builtin_amdgcn_cvt_pk_fp8_f32(f0, f1, 0, false);
                    w0     = __builtin_amdgcn_cvt_pk_fp8_f32(f2, f3, w0, true);
                    int w1 = __builtin_amdgcn_cvt_pk_fp8_f32(f4, f5, 0, false);
                    w1     = __builtin_amdgcn_cvt_pk_fp8_f32(f6, f7, w1, true);
                    int off = (ck < 32) ? (ck - 16) * 16 : ((ck - 32) * 16 + 8);
                    *reinterpret_cast<int2*>(kv8 + (size_t)grow * 256 + off) =
                        make_int2(w0, w1);
                } else {                           // skip -> qs at +128
                    *reinterpret_cast<short8v*>(&qs[(size_t)grow * 256 + 128 + (ck - 48) * 8]) =
                        *reinterpret_cast<const short8v*>(&Clds[rl * CSTR + ck * 8]);
                }
            }
        }
    }
}

// ---------------- input GEMM: barrier-free, W direct from L2 ---------------
__global__ __launch_bounds__(128) void gemm_in(
    const float* __restrict__ Af, const short* __restrict__ Wt0,
    const float* __restrict__ bias, short* __restrict__ out, int nrows)
{
    constexpr int CSTR = 132;
    __shared__ short Clds[16 * CSTR];      // 4.2KB

    const int tid  = threadIdx.x;
    const int lane = tid & 63;
    const int wid  = tid >> 6;             // 0..1 -> col half
    const int n0   = wid * 64;
    const int lg   = lane >> 4;
    const int l15  = lane & 15;
    const int rb   = blockIdx.x * 64;
    const int r0   = rb + l15;

    f32x4 acc[4][4];
#pragma unroll
    for (int i = 0; i < 4; ++i)
#pragma unroll
        for (int j = 0; j < 4; ++j) acc[i][j] = {0.f, 0.f, 0.f, 0.f};

    const short8v zero8 = {0, 0, 0, 0, 0, 0, 0, 0};

#pragma unroll
    for (int s = 0; s < 4; ++s) {
        short8v a[4], b[4];
#pragma unroll
        for (int mf = 0; mf < 4; ++mf) {
            int row = r0 + mf * 16;
            if (row < nrows) {
                const float* ap = Af + (size_t)row * HID + s * 32 + lg * 8;
                float4 f0 = *reinterpret_cast<const float4*>(ap);
                float4 f1 = *reinterpret_cast<const float4*>(ap + 4);
                short8v t;
                t[0] = (short)f2bf(f0.x); t[1] = (short)f2bf(f0.y);
                t[2] = (short)f2bf(f0.z); t[3] = (short)f2bf(f0.w);
                t[4] = (short)f2bf(f1.x); t[5] = (short)f2bf(f1.y);
                t[6] = (short)f2bf(f1.z); t[7] = (short)f2bf(f1.w);
                a[mf] = t;
            } else a[mf] = zero8;
        }
        const int kb = s * 4 + lg;
#pragma unroll
        for (int nf = 0; nf < 4; ++nf) {
            int col = n0 + nf * 16 + l15;
            b[nf] = *reinterpret_cast<const short8v*>(&Wt0[((size_t)kb * 128 + col) * 8]);
        }
#pragma unroll
        for (int mf = 0; mf < 4; ++mf)
#pragma unroll
            for (int nf = 0; nf < 4; ++nf)
                acc[mf][nf] = __builtin_amdgcn_mfma_f32_16x16x32_bf16(
                    a[mf], b[nf], acc[mf][nf], 0, 0, 0);
    }

#pragma unroll
    for (int mf = 0; mf < 4; ++mf) {
        __syncthreads();
#pragma unroll
        for (int nf = 0; nf < 4; ++nf) {
            int col = n0 + nf * 16 + l15;
            float bv = bias[col];
#pragma unroll
            for (int qq = 0; qq < 4; ++qq) {
                int rl = lg * 4 + qq;              // 0..15
                Clds[rl * CSTR + col] = (short)f2bf(acc[mf][nf][qq] + bv);
            }
        }
        __syncthreads();
#pragma unroll
        for (int i = 0; i < 2; ++i) {              // 16 rows * 16 chunks / 128
            int c = tid + 128 * i;
            int rl = c >> 4;
            int ck = c & 15;
            int grow = rb + mf * 16 + rl;
            if (grow < nrows)
                *reinterpret_cast<short8v*>(&out[(size_t)grow * HID + ck * 8]) =
                    *reinterpret_cast<const short8v*>(&Clds[rl * CSTR + ck * 8]);
        }
    }
}

// ---------------- CSR build ----------------
__global__ __launch_bounds__(256) void count_deg_kernel(
    const int* __restrict__ dst, int* __restrict__ deg,
    unsigned short* __restrict__ rank16, int ne)
{
    int e = blockIdx.x * 256 + threadIdx.x;
    if (e < ne) {
        int r = atomicAdd(&deg[dst[e]], 1);
        rank16[e] = (unsigned short)r;
    }
}

__global__ __launch_bounds__(1024) void scan1_kernel(
    const int* __restrict__ deg, int* __restrict__ offsets,
    int* __restrict__ bsum, int n)
{
    __shared__ int wsum[16];
    const int tid = threadIdx.x, wid = tid >> 6, lane = tid & 63;
    int i = blockIdx.x * 1024 + tid;
    int val = (i < n) ? deg[i] : 0;
    int x = val;
#pragma unroll
    for (int off = 1; off < 64; off <<= 1) {
        int y = __shfl_up(x, off);
        if (lane >= off) x += y;
    }
    if (lane == 63) wsum[wid] = x;
    __syncthreads();
    if (tid < 16) {
        int w = wsum[tid];
#pragma unroll
        for (int off = 1; off < 16; off <<= 1) {
            int y = __shfl_up(w, off);
            if (tid >= off) w += y;
        }
        wsum[tid] = w;
    }
    __syncthreads();
    int incl = x + (wid ? wsum[wid - 1] : 0);
    if (i < n) offsets[i + 1] = incl;
    if (tid == 1023) bsum[blockIdx.x] = incl;
}

__global__ __launch_bounds__(256) void scan3_kernel(
    int* __restrict__ offsets, const int* __restrict__ bsum, int n, int nb)
{
    __shared__ int sx[64];
    const int tid = threadIdx.x;
    if (tid < 64) {
        int vv = (tid < nb) ? bsum[tid] : 0;
        int x = vv;
#pragma unroll
        for (int off = 1; off < 64; off <<= 1) {
            int y = __shfl_up(x, off);
            if (tid >= off) x += y;
        }
        sx[tid] = x - vv;   // exclusive prefix of block sums
    }
    __syncthreads();
    int i = blockIdx.x * 256 + tid;
    if (i >= n) return;
    offsets[i + 1] += sx[i >> 10];
    if (i == 0) offsets[0] = 0;
}

__global__ __launch_bounds__(256) void scatter_kernel(
    const int* __restrict__ src, const int* __restrict__ dst,
    const int* __restrict__ offsets, const unsigned short* __restrict__ rank16,
    unsigned short* __restrict__ csr16, int ne)
{
    int e = blockIdx.x * 256 + threadIdx.x;
    if (e < ne) {
        int pos = offsets[dst[e]] + rank16[e];
        csr16[pos] = (unsigned short)src[e];
    }
}

// ---------------- graph boundary search (batch sorted) ----------------
__global__ __launch_bounds__(128) void gstart_kernel(
    const int* __restrict__ batch, int* __restrict__ gstart, int n)
{
    int t = threadIdx.x;
    if (t > NG) return;
    int lo = 0, hi = n;
    while (lo < hi) {
        int mid = (lo + hi) >> 1;
        if (batch[mid] < t) lo = mid + 1; else hi = mid;
    }
    gstart[t] = lo;   // first index with batch[i] >= t; gstart[NG] = n
}

// ---------------- fused attention + skip + ReLU ----------------
__global__ __launch_bounds__(256) void attn_kernel(
    const short* __restrict__ qs, const signed char* __restrict__ kv8,
    const int* __restrict__ offsets, const unsigned short* __restrict__ csr16,
    short* __restrict__ hout, int nnodes)
{
    int node = (blockIdx.x * 256 + threadIdx.x) >> 6;
    if (node >= nnodes) return;
    const int lane = threadIdx.x & 63;
    const int grp = lane >> 4;        // edge slot 0..3
    const int g   = lane & 15;        // dims 8g..8g+7 (head = g/4)
    const float scale = 0.17677669529663687f; // 1/sqrt(32)

    const size_t nb = (size_t)node * 256;
    short8v q8 = *reinterpret_cast<const short8v*>(&qs[nb + g * 8]);
    float qf[8];
#pragma unroll
    for (int i = 0; i < 8; ++i) qf[i] = bf2f((unsigned short)q8[i]);

    int e0 = offsets[node], e1 = offsets[node + 1];
    float s = 0.f;
    float acc[8] = {0.f, 0.f, 0.f, 0.f, 0.f, 0.f, 0.f, 0.f};

    const signed char* kvb = kv8 + g * 16;

    int e = e0 + grp;
    int i0 = (e < e1)     ? (int)csr16[e]     : 0;
    int i1 = (e + 4 < e1) ? (int)csr16[e + 4] : 0;

    for (; e + 4 < e1; e += 8) {
        int j0 = (e + 8  < e1) ? (int)csr16[e + 8]  : 0;   // prefetch next pair
        int j1 = (e + 12 < e1) ? (int)csr16[e + 12] : 0;
        int4 kv0 = *reinterpret_cast<const int4*>(kvb + ((size_t)i0 << 8));
        int4 kv1 = *reinterpret_cast<const int4*>(kvb + ((size_t)i1 << 8));
        float p0 = dot8_fp8(kv0.x, kv0.y, qf);
        float p1 = dot8_fp8(kv1.x, kv1.y, qf);
        p0 += __shfl_xor(p0, 1);  p1 += __shfl_xor(p1, 1);
        p0 += __shfl_xor(p0, 2);  p1 += __shfl_xor(p1, 2);
        float w0 = __expf(fminf(p0 * scale, 60.f));
        float w1 = __expf(fminf(p1 * scale, 60.f));
        s += w0 + w1;
        acc8_fp8(kv0.z, kv0.w, w0, acc);
        acc8_fp8(kv1.z, kv1.w, w1, acc);
        i0 = j0; i1 = j1;
    }
    if (e < e1) {
        int4 kv0 = *reinterpret_cast<const int4*>(kvb + ((size_t)i0 << 8));
        float p0 = dot8_fp8(kv0.x, kv0.y, qf);
        p0 += __shfl_xor(p0, 1);
        p0 += __shfl_xor(p0, 2);
        float w0 = __expf(fminf(p0 * scale, 60.f));
        s += w0;
        acc8_fp8(kv0.z, kv0.w, w0, acc);
    }

    // merge the 4 edge slots (once per node)
#pragma unroll
    for (int off = 16; off <= 32; off <<= 1) {
        s += __shfl_xor(s, off);
#pragma unroll
        for (int i = 0; i < 8; ++i) acc[i] += __shfl_xor(acc[i], off);
    }
    float inv = 1.f / (s + 1e-16f);
    short8v sk8 = *reinterpret_cast<const short8v*>(&qs[nb + 128 + g * 8]);
    short8v o;
#pragma unroll
    for (int i = 0; i < 8; ++i) {
        float ov = fmaxf(acc[i] * inv + bf2f((unsigned short)sk8[i]), 0.f);
        o[i] = (short)f2bf(ov);
    }
    *reinterpret_cast<short8v*>(&hout[(size_t)node * HID + g * 8]) = o;
}

// ---------------- pooling: block per (graph, row-chunk), LDS reduce --------
// 64 graphs x 8 chunks = 512 blocks; 16 row-streams x 16 col-groups; one
// atomicAdd per column per block (65K total, contention-free).
__global__ __launch_bounds__(256) void pool_kernel(
    const short* __restrict__ h, const int* __restrict__ gstart,
    float* __restrict__ pooled)
{
    __shared__ float sdata[16][HID];
    const int g  = blockIdx.x >> 3;        // graph
    const int rc = blockIdx.x & 7;         // row chunk
    const int rg = threadIdx.x >> 4;       // 16 row streams
    const int c8 = threadIdx.x & 15;       // 8 cols each
    const int n0 = gstart[g], n1 = gstart[g + 1];

    float s[8] = {0.f, 0.f, 0.f, 0.f, 0.f, 0.f, 0.f, 0.f};
    for (int n = n0 + rc * 16 + rg; n < n1; n += 128) {
        short8v hv = *reinterpret_cast<const short8v*>(&h[(size_t)n * HID + c8 * 8]);
#pragma unroll
        for (int i = 0; i < 8; ++i) s[i] += bf2f((unsigned short)hv[i]);
    }
#pragma unroll
    for (int i = 0; i < 8; ++i) sdata[rg][c8 * 8 + i] = s[i];
    __syncthreads();
    if (threadIdx.x < HID) {
        float sum = 0.f;
#pragma unroll
        for (int r = 0; r < 16; ++r) sum += sdata[r][threadIdx.x];
        atomicAdd(&pooled[g * HID + threadIdx.x], sum);
    }
}

// ---------------- final FC ----------------
__global__ __launch_bounds__(256) void fc_kernel(
    const float* __restrict__ pooled, const float* __restrict__ Wfc,
    const float* __restrict__ bfc, float* __restrict__ out)
{
    int t = blockIdx.x * 256 + threadIdx.x;   // 4096 = G*LAT
    if (t >= NG * LAT) return;
    int g = t >> 6, o = t & 63;
    float sum = bfc[o];
    for (int j = 0; j < HID; j += 4) {
        float4 p = *reinterpret_cast<const float4*>(&pooled[g * HID + j]);
        float4 w = *reinterpret_cast<const float4*>(&Wfc[o * HID + j]);
        sum += p.x * w.x + p.y * w.y + p.z * w.z + p.w * w.w;
    }
    out[t] = sum;
}

extern "C" void kernel_launch(void* const* d_in, const int* in_sizes, int n_in,
                              void* d_out, int out_size, void* d_ws, size_t ws_size,
                              hipStream_t stream)
{
    const float* x     = (const float*)d_in[0];
    const int*   ei    = (const int*)d_in[1];
    const int*   batch = (const int*)d_in[2];
    const float* Win   = (const float*)d_in[3];
    const float* bin_  = (const float*)d_in[4];
    const float* Wq    = (const float*)d_in[5];
    const float* bq    = (const float*)d_in[6];
    const float* Wk    = (const float*)d_in[7];
    const float* bk    = (const float*)d_in[8];
    const float* Wv    = (const float*)d_in[9];
    const float* bv    = (const float*)d_in[10];
    const float* Wskip = (const float*)d_in[11];
    const float* bskip = (const float*)d_in[12];
    const float* Wfc   = (const float*)d_in[13];
    const float* bfc   = (const float*)d_in[14];
    float* out = (float*)d_out;

    // workspace layout (~57 MB), 256B-aligned chunks
    char* ws = (char*)d_ws;
    auto alloc = [&](size_t bytes) {
        void* p = (void*)ws;
        ws += (bytes + 255) & ~(size_t)255;
        return p;
    };
    short* hb     = (short*)alloc((size_t)NN * HID * 2);
    short* qs     = (short*)alloc((size_t)NN * 256 * 2);   // Q(128) + skip(128)
    signed char* kv8 = (signed char*)alloc((size_t)NN * 256); // fp8 K|V interleaved
    short* Wt0    = (short*)alloc((size_t)16384 * 2);      // input Win transposed
    short* Wt     = (short*)alloc((size_t)12 * 16384 * 2); // layer W transposed
    float* bcat   = (float*)alloc((size_t)13 * 128 * 4);
    float* pooled = (float*)alloc((size_t)NG * HID * 4);
    int* deg      = (int*)alloc((size_t)NN * 4);
    int* offsets  = (int*)alloc((size_t)(NN + 1) * 4);
    int* bsum     = (int*)alloc((size_t)64 * 4);
    int* gstart   = (int*)alloc((size_t)(NG + 1) * 4);
    unsigned short* rank16 = (unsigned short*)alloc((size_t)NE * 2);
    unsigned short* csr16  = (unsigned short*)alloc((size_t)NE * 2);

    const int* esrc = ei;
    const int* edst = ei + NE;

    PtrTab wt, bt;
    wt.p[0] = Win; bt.p[0] = bin_;
    for (int l = 0; l < NL; ++l) {
        wt.p[1 + 4 * l] = Wq    + (size_t)l * HID * HID;
        wt.p[2 + 4 * l] = Wk    + (size_t)l * HID * HID;
        wt.p[3 + 4 * l] = Wv    + (size_t)l * HID * HID;
        wt.p[4 + 4 * l] = Wskip + (size_t)l * HID * HID;
        bt.p[1 + 4 * l] = bq    + (size_t)l * HID;
        bt.p[2 + 4 * l] = bk    + (size_t)l * HID;
        bt.p[3 + 4 * l] = bv    + (size_t)l * HID;
        bt.p[4 + 4 * l] = bskip + (size_t)l * HID;
    }

    pack_all_kernel<<<(12 * 16384 + 255) / 256, 256, 0, stream>>>(
        wt, bt, Wt0, Wt, bcat, deg, pooled);

    const int egrid = (NE + 255) / 256;
    const int nsb = (NN + 1023) / 1024;   // 49
    count_deg_kernel<<<egrid, 256, 0, stream>>>(edst, deg, rank16, NE);
    scan1_kernel<<<nsb, 1024, 0, stream>>>(deg, offsets, bsum, NN);
    scan3_kernel<<<(NN + 255) / 256, 256, 0, stream>>>(offsets, bsum, NN, nsb);
    scatter_kernel<<<egrid, 256, 0, stream>>>(esrc, edst, offsets, rank16, csr16, NE);
    gstart_kernel<<<1, 128, 0, stream>>>(batch, gstart, NN);

    // input projection: h = x @ Win^T + bin (fp32 A converted on load)
    const int gl = (NN + 63) / 64;        // 782
    gemm_in<<<gl, 128, 0, stream>>>(x, Wt0, bcat, hb, NN);

    for (int l = 0; l < NL; ++l) {
        gemm_layer<<<gl, 512, 0, stream>>>(
            hb, Wt + (size_t)l * 16 * 512 * 8, bcat + (1 + 4 * l) * 128, qs, kv8, NN);
        attn_kernel<<<(NN + 3) / 4, 256, 0, stream>>>(qs, kv8, offsets, csr16, hb, NN);
    }

    pool_kernel<<<NG * 8, 256, 0, stream>>>(hb, gstart, pooled);
    fc_kernel<<<16, 256, 0, stream>>>(pooled, Wfc, bfc, out);
}

// Round 15
// 283.330 us; speedup vs baseline: 1.1820x; 1.0112x over previous
//
#include <hip/hip_runtime.h>
#include <math.h>

#define NN 50000
#define NE 800000
#define HID 128
#define NL 3
#define NG 64
#define LAT 64

typedef __attribute__((ext_vector_type(8))) short short8v;
typedef __attribute__((ext_vector_type(4))) short short4v;
typedef __attribute__((ext_vector_type(4))) float f32x4;
typedef __attribute__((ext_vector_type(2))) float f32x2;

__device__ __forceinline__ float bf2f(unsigned short b) {
    unsigned u = ((unsigned)b) << 16;
    return __builtin_bit_cast(float, u);
}
__device__ __forceinline__ unsigned short f2bf(float f) {
    unsigned u = __builtin_bit_cast(unsigned, f);
    u += 0x7FFFu + ((u >> 16) & 1u);   // round-to-nearest-even
    return (unsigned short)(u >> 16);
}

// decode 8 fp8 e4m3 (two dwords) against qf[8]: dot product
__device__ __forceinline__ float dot8_fp8(int d0, int d1, const float* qf) {
    f32x2 a01 = __builtin_amdgcn_cvt_pk_f32_fp8(d0, false);
    f32x2 a23 = __builtin_amdgcn_cvt_pk_f32_fp8(d0, true);
    f32x2 a45 = __builtin_amdgcn_cvt_pk_f32_fp8(d1, false);
    f32x2 a67 = __builtin_amdgcn_cvt_pk_f32_fp8(d1, true);
    return a01[0]*qf[0] + a01[1]*qf[1] + a23[0]*qf[2] + a23[1]*qf[3]
         + a45[0]*qf[4] + a45[1]*qf[5] + a67[0]*qf[6] + a67[1]*qf[7];
}
// decode 8 fp8 e4m3 (two dwords), acc += wgt * v
__device__ __forceinline__ void acc8_fp8(int d0, int d1, float wgt, float* acc) {
    f32x2 v01 = __builtin_amdgcn_cvt_pk_f32_fp8(d0, false);
    f32x2 v23 = __builtin_amdgcn_cvt_pk_f32_fp8(d0, true);
    f32x2 v45 = __builtin_amdgcn_cvt_pk_f32_fp8(d1, false);
    f32x2 v67 = __builtin_amdgcn_cvt_pk_f32_fp8(d1, true);
    acc[0] += wgt * v01[0]; acc[1] += wgt * v01[1];
    acc[2] += wgt * v23[0]; acc[3] += wgt * v23[1];
    acc[4] += wgt * v45[0]; acc[5] += wgt * v45[1];
    acc[6] += wgt * v67[0]; acc[7] += wgt * v67[1];
}

struct PtrTab { const float* p[13]; };

// ---------------- merged preamble: pack W (transposed) + count_deg + gstart -
// Blocks [0,768): pack; [768, 768+3125): count_deg+rank; last block: gstart.
// deg/pooled are zeroed by hipMemsetAsync BEFORE this kernel (no race).
#define PACK_BLOCKS 768
#define CD_BLOCKS   ((NE + 255) / 256)
__global__ __launch_bounds__(256) void preamble_kernel(
    PtrTab wt, PtrTab bt, short* __restrict__ Wt0, short* __restrict__ Wt,
    float* __restrict__ bcat,
    const int* __restrict__ edst, int* __restrict__ deg,
    unsigned short* __restrict__ rank16,
    const int* __restrict__ batch, int* __restrict__ gstart)
{
    const int b = blockIdx.x;
    if (b < PACK_BLOCKS) {
        int gid = b * 256 + threadIdx.x;               // covers 12*16384
        if (gid < 16384) {                             // input Win, transposed
            int i  = gid & 7;
            int j  = (gid >> 3) & 127;
            int kb = gid >> 10;
            Wt0[gid] = (short)f2bf(wt.p[0][j * 128 + kb * 8 + i]);
        }
        if (gid < 12 * 16384) {                        // layer W, transposed
            int i  = gid & 7;
            int c  = (gid >> 3) & 511;
            int kb = (gid >> 12) & 15;
            int l  = gid >> 16;
            int slot = 1 + 4 * l + (c >> 7);
            int elem = (c & 127) * 128 + kb * 8 + i;
            Wt[gid] = (short)f2bf(wt.p[slot][elem]);
        }
        if (gid < 13 * 128) {
            int slot = gid >> 7, e = gid & 127;
            bcat[gid] = bt.p[slot][e];
        }
    } else if (b < PACK_BLOCKS + CD_BLOCKS) {
        int e = (b - PACK_BLOCKS) * 256 + threadIdx.x;
        if (e < NE) {
            int r = atomicAdd(&deg[edst[e]], 1);
            rank16[e] = (unsigned short)r;
        }
    } else {
        int t = threadIdx.x;
        if (t <= NG) {
            int lo = 0, hi = NN;
            while (lo < hi) {
                int mid = (lo + hi) >> 1;
                if (batch[mid] < t) lo = mid + 1; else hi = mid;
            }
            gstart[t] = lo;
        }
    }
}

// ---------------- layer GEMM: barrier-free, W direct from L2 (R12-proven) --
__global__ __launch_bounds__(512) void gemm_layer(
    const short* __restrict__ A, const short* __restrict__ Wt_l,
    const float* __restrict__ bias, short* __restrict__ qs,
    signed char* __restrict__ kv8, int nrows)
{
    constexpr int CSTR = 516;
    __shared__ short Clds[16 * CSTR];      // 16.5KB

    const int tid  = threadIdx.x;
    const int lane = tid & 63;
    const int wid  = tid >> 6;             // 0..7 -> col group
    const int n0   = wid * 64;
    const int lg   = lane >> 4;
    const int l15  = lane & 15;
    const int rb   = blockIdx.x * 64;
    const int r0   = rb + l15;

    f32x4 acc[4][4];
#pragma unroll
    for (int i = 0; i < 4; ++i)
#pragma unroll
        for (int j = 0; j < 4; ++j) acc[i][j] = {0.f, 0.f, 0.f, 0.f};

    const short8v zero8 = {0, 0, 0, 0, 0, 0, 0, 0};

#pragma unroll
    for (int s = 0; s < 4; ++s) {
        short8v a[4], b[4];
#pragma unroll
        for (int mf = 0; mf < 4; ++mf) {
            int row = r0 + mf * 16;
            a[mf] = (row < nrows)
                ? *reinterpret_cast<const short8v*>(&A[(size_t)row * HID + s * 32 + lg * 8])
                : zero8;
        }
        const int kb = s * 4 + lg;
#pragma unroll
        for (int nf = 0; nf < 4; ++nf) {
            int col = n0 + nf * 16 + l15;
            b[nf] = *reinterpret_cast<const short8v*>(&Wt_l[((size_t)kb * 512 + col) * 8]);
        }
#pragma unroll
        for (int mf = 0; mf < 4; ++mf)
#pragma unroll
            for (int nf = 0; nf < 4; ++nf)
                acc[mf][nf] = __builtin_amdgcn_mfma_f32_16x16x32_bf16(
                    a[mf], b[nf], acc[mf][nf], 0, 0, 0);
    }

    // ---- epilogue: 4 passes of 16 rows through LDS ----
#pragma unroll
    for (int mf = 0; mf < 4; ++mf) {
        __syncthreads();
#pragma unroll
        for (int nf = 0; nf < 4; ++nf) {
            int col = n0 + nf * 16 + l15;
            float bv = bias[col];
#pragma unroll
            for (int qq = 0; qq < 4; ++qq) {
                int rl = lg * 4 + qq;              // 0..15
                Clds[rl * CSTR + col] = (short)f2bf(acc[mf][nf][qq] + bv);
            }
        }
        __syncthreads();
#pragma unroll
        for (int i = 0; i < 2; ++i) {              // 16 rows * 64 chunks / 512
            int c = tid + 512 * i;
            int rl = c >> 6;
            int ck = c & 63;
            int grow = rb + mf * 16 + rl;
            if (grow < nrows) {
                if (ck < 16) {                     // Q -> qs (stride 256)
                    *reinterpret_cast<short8v*>(&qs[(size_t)grow * 256 + ck * 8]) =
                        *reinterpret_cast<const short8v*>(&Clds[rl * CSTR + ck * 8]);
                } else if (ck < 48) {              // K/V -> fp8 interleaved
                    short8v cv = *reinterpret_cast<const short8v*>(&Clds[rl * CSTR + ck * 8]);
                    float f0 = bf2f((unsigned short)cv[0]), f1 = bf2f((unsigned short)cv[1]);
                    float f2 = bf2f((unsigned short)cv[2]), f3 = bf2f((unsigned short)cv[3]);
                    float f4 = bf2f((unsigned short)cv[4]), f5 = bf2f((unsigned short)cv[5]);
                    float f6 = bf2f((unsigned short)cv[6]), f7 = bf2f((unsigned short)cv[7]);
                    int w0 = __builtin_amdgcn_cvt_pk_fp8_f32(f0, f1, 0, false);
                    w0     = __builtin_amdgcn_cvt_pk_fp8_f32(f2, f3, w0, true);
                    int w1 = __builtin_amdgcn_cvt_pk_fp8_f32(f4, f5, 0, false);
                    w1     = __builtin_amdgcn_cvt_pk_fp8_f32(f6, f7, w1, true);
                    int off = (ck < 32) ? (ck - 16) * 16 : ((ck - 32) * 16 + 8);
                    *reinterpret_cast<int2*>(kv8 + (size_t)grow * 256 + off) =
                        make_int2(w0, w1);
                } else {                           // skip -> qs at +128
                    *reinterpret_cast<short8v*>(&qs[(size_t)grow * 256 + 128 + (ck - 48) * 8]) =
                        *reinterpret_cast<const short8v*>(&Clds[rl * CSTR + ck * 8]);
                }
            }
        }
    }
}

// ---------------- input GEMM: barrier-free, W direct from L2 ---------------
__global__ __launch_bounds__(128) void gemm_in(
    const float* __restrict__ Af, const short* __restrict__ Wt0,
    const float* __restrict__ bias, short* __restrict__ out, int nrows)
{
    constexpr int CSTR = 132;
    __shared__ short Clds[16 * CSTR];      // 4.2KB

    const int tid  = threadIdx.x;
    const int lane = tid & 63;
    const int wid  = tid >> 6;             // 0..1 -> col half
    const int n0   = wid * 64;
    const int lg   = lane >> 4;
    const int l15  = lane & 15;
    const int rb   = blockIdx.x * 64;
    const int r0   = rb + l15;

    f32x4 acc[4][4];
#pragma unroll
    for (int i = 0; i < 4; ++i)
#pragma unroll
        for (int j = 0; j < 4; ++j) acc[i][j] = {0.f, 0.f, 0.f, 0.f};

    const short8v zero8 = {0, 0, 0, 0, 0, 0, 0, 0};

#pragma unroll
    for (int s = 0; s < 4; ++s) {
        short8v a[4], b[4];
#pragma unroll
        for (int mf = 0; mf < 4; ++mf) {
            int row = r0 + mf * 16;
            if (row < nrows) {
                const float* ap = Af + (size_t)row * HID + s * 32 + lg * 8;
                float4 f0 = *reinterpret_cast<const float4*>(ap);
                float4 f1 = *reinterpret_cast<const float4*>(ap + 4);
                short8v t;
                t[0] = (short)f2bf(f0.x); t[1] = (short)f2bf(f0.y);
                t[2] = (short)f2bf(f0.z); t[3] = (short)f2bf(f0.w);
                t[4] = (short)f2bf(f1.x); t[5] = (short)f2bf(f1.y);
                t[6] = (short)f2bf(f1.z); t[7] = (short)f2bf(f1.w);
                a[mf] = t;
            } else a[mf] = zero8;
        }
        const int kb = s * 4 + lg;
#pragma unroll
        for (int nf = 0; nf < 4; ++nf) {
            int col = n0 + nf * 16 + l15;
            b[nf] = *reinterpret_cast<const short8v*>(&Wt0[((size_t)kb * 128 + col) * 8]);
        }
#pragma unroll
        for (int mf = 0; mf < 4; ++mf)
#pragma unroll
            for (int nf = 0; nf < 4; ++nf)
                acc[mf][nf] = __builtin_amdgcn_mfma_f32_16x16x32_bf16(
                    a[mf], b[nf], acc[mf][nf], 0, 0, 0);
    }

#pragma unroll
    for (int mf = 0; mf < 4; ++mf) {
        __syncthreads();
#pragma unroll
        for (int nf = 0; nf < 4; ++nf) {
            int col = n0 + nf * 16 + l15;
            float bv = bias[col];
#pragma unroll
            for (int qq = 0; qq < 4; ++qq) {
                int rl = lg * 4 + qq;              // 0..15
                Clds[rl * CSTR + col] = (short)f2bf(acc[mf][nf][qq] + bv);
            }
        }
        __syncthreads();
#pragma unroll
        for (int i = 0; i < 2; ++i) {              // 16 rows * 16 chunks / 128
            int c = tid + 128 * i;
            int rl = c >> 4;
            int ck = c & 15;
            int grow = rb + mf * 16 + rl;
            if (grow < nrows)
                *reinterpret_cast<short8v*>(&out[(size_t)grow * HID + ck * 8]) =
                    *reinterpret_cast<const short8v*>(&Clds[rl * CSTR + ck * 8]);
        }
    }
}

// ---------------- scans + scatter ----------------
__global__ __launch_bounds__(1024) void scan1_kernel(
    const int* __restrict__ deg, int* __restrict__ offsets,
    int* __restrict__ bsum, int n)
{
    __shared__ int wsum[16];
    const int tid = threadIdx.x, wid = tid >> 6, lane = tid & 63;
    int i = blockIdx.x * 1024 + tid;
    int val = (i < n) ? deg[i] : 0;
    int x = val;
#pragma unroll
    for (int off = 1; off < 64; off <<= 1) {
        int y = __shfl_up(x, off);
        if (lane >= off) x += y;
    }
    if (lane == 63) wsum[wid] = x;
    __syncthreads();
    if (tid < 16) {
        int w = wsum[tid];
#pragma unroll
        for (int off = 1; off < 16; off <<= 1) {
            int y = __shfl_up(w, off);
            if (tid >= off) w += y;
        }
        wsum[tid] = w;
    }
    __syncthreads();
    int incl = x + (wid ? wsum[wid - 1] : 0);
    if (i < n) offsets[i + 1] = incl;
    if (tid == 1023) bsum[blockIdx.x] = incl;
}

__global__ __launch_bounds__(256) void scan3_kernel(
    int* __restrict__ offsets, const int* __restrict__ bsum, int n, int nb)
{
    __shared__ int sx[64];
    const int tid = threadIdx.x;
    if (tid < 64) {
        int vv = (tid < nb) ? bsum[tid] : 0;
        int x = vv;
#pragma unroll
        for (int off = 1; off < 64; off <<= 1) {
            int y = __shfl_up(x, off);
            if (tid >= off) x += y;
        }
        sx[tid] = x - vv;   // exclusive prefix of block sums
    }
    __syncthreads();
    int i = blockIdx.x * 256 + tid;
    if (i >= n) return;
    offsets[i + 1] += sx[i >> 10];
    if (i == 0) offsets[0] = 0;
}

__global__ __launch_bounds__(256) void scatter_kernel(
    const int* __restrict__ src, const int* __restrict__ dst,
    const int* __restrict__ offsets, const unsigned short* __restrict__ rank16,
    unsigned short* __restrict__ csr16, int ne)
{
    int e = blockIdx.x * 256 + threadIdx.x;
    if (e < ne) {
        int pos = offsets[dst[e]] + rank16[e];
        csr16[pos] = (unsigned short)src[e];
    }
}

// ---------------- fused attention + skip + ReLU ----------------
__global__ __launch_bounds__(256) void attn_kernel(
    const short* __restrict__ qs, const signed char* __restrict__ kv8,
    const int* __restrict__ offsets, const unsigned short* __restrict__ csr16,
    short* __restrict__ hout, int nnodes)
{
    int node = (blockIdx.x * 256 + threadIdx.x) >> 6;
    if (node >= nnodes) return;
    const int lane = threadIdx.x & 63;
    const int grp = lane >> 4;        // edge slot 0..3
    const int g   = lane & 15;        // dims 8g..8g+7 (head = g/4)
    const float scale = 0.17677669529663687f; // 1/sqrt(32)

    const size_t nb = (size_t)node * 256;
    short8v q8 = *reinterpret_cast<const short8v*>(&qs[nb + g * 8]);
    float qf[8];
#pragma unroll
    for (int i = 0; i < 8; ++i) qf[i] = bf2f((unsigned short)q8[i]);

    int e0 = offsets[node], e1 = offsets[node + 1];
    float s = 0.f;
    float acc[8] = {0.f, 0.f, 0.f, 0.f, 0.f, 0.f, 0.f, 0.f};

    const signed char* kvb = kv8 + g * 16;

    int e = e0 + grp;
    int i0 = (e < e1)     ? (int)csr16[e]     : 0;
    int i1 = (e + 4 < e1) ? (int)csr16[e + 4] : 0;

    for (; e + 4 < e1; e += 8) {
        int j0 = (e + 8  < e1) ? (int)csr16[e + 8]  : 0;   // prefetch next pair
        int j1 = (e + 12 < e1) ? (int)csr16[e + 12] : 0;
        int4 kv0 = *reinterpret_cast<const int4*>(kvb + ((size_t)i0 << 8));
        int4 kv1 = *reinterpret_cast<const int4*>(kvb + ((size_t)i1 << 8));
        float p0 = dot8_fp8(kv0.x, kv0.y, qf);
        float p1 = dot8_fp8(kv1.x, kv1.y, qf);
        p0 += __shfl_xor(p0, 1);  p1 += __shfl_xor(p1, 1);
        p0 += __shfl_xor(p0, 2);  p1 += __shfl_xor(p1, 2);
        float w0 = __expf(fminf(p0 * scale, 60.f));
        float w1 = __expf(fminf(p1 * scale, 60.f));
        s += w0 + w1;
        acc8_fp8(kv0.z, kv0.w, w0, acc);
        acc8_fp8(kv1.z, kv1.w, w1, acc);
        i0 = j0; i1 = j1;
    }
    if (e < e1) {
        int4 kv0 = *reinterpret_cast<const int4*>(kvb + ((size_t)i0 << 8));
        float p0 = dot8_fp8(kv0.x, kv0.y, qf);
        p0 += __shfl_xor(p0, 1);
        p0 += __shfl_xor(p0, 2);
        float w0 = __expf(fminf(p0 * scale, 60.f));
        s += w0;
        acc8_fp8(kv0.z, kv0.w, w0, acc);
    }

    // merge the 4 edge slots (once per node)
#pragma unroll
    for (int off = 16; off <= 32; off <<= 1) {
        s += __shfl_xor(s, off);
#pragma unroll
        for (int i = 0; i < 8; ++i) acc[i] += __shfl_xor(acc[i], off);
    }
    float inv = 1.f / (s + 1e-16f);
    short8v sk8 = *reinterpret_cast<const short8v*>(&qs[nb + 128 + g * 8]);
    short8v o;
#pragma unroll
    for (int i = 0; i < 8; ++i) {
        float ov = fmaxf(acc[i] * inv + bf2f((unsigned short)sk8[i]), 0.f);
        o[i] = (short)f2bf(ov);
    }
    *reinterpret_cast<short8v*>(&hout[(size_t)node * HID + g * 8]) = o;
}

// ---------------- pooling: block per (graph, row-chunk), LDS reduce --------
__global__ __launch_bounds__(256) void pool_kernel(
    const short* __restrict__ h, const int* __restrict__ gstart,
    float* __restrict__ pooled)
{
    __shared__ float sdata[16][HID];
    const int g  = blockIdx.x >> 3;        // graph
    const int rc = blockIdx.x & 7;         // row chunk
    const int rg = threadIdx.x >> 4;       // 16 row streams
    const int c8 = threadIdx.x & 15;       // 8 cols each
    const int n0 = gstart[g], n1 = gstart[g + 1];

    float s[8] = {0.f, 0.f, 0.f, 0.f, 0.f, 0.f, 0.f, 0.f};
    for (int n = n0 + rc * 16 + rg; n < n1; n += 128) {
        short8v hv = *reinterpret_cast<const short8v*>(&h[(size_t)n * HID + c8 * 8]);
#pragma unroll
        for (int i = 0; i < 8; ++i) s[i] += bf2f((unsigned short)hv[i]);
    }
#pragma unroll
    for (int i = 0; i < 8; ++i) sdata[rg][c8 * 8 + i] = s[i];
    __syncthreads();
    if (threadIdx.x < HID) {
        float sum = 0.f;
#pragma unroll
        for (int r = 0; r < 16; ++r) sum += sdata[r][threadIdx.x];
        atomicAdd(&pooled[g * HID + threadIdx.x], sum);
    }
}

// ---------------- final FC ----------------
__global__ __launch_bounds__(256) void fc_kernel(
    const float* __restrict__ pooled, const float* __restrict__ Wfc,
    const float* __restrict__ bfc, float* __restrict__ out)
{
    int t = blockIdx.x * 256 + threadIdx.x;   // 4096 = G*LAT
    if (t >= NG * LAT) return;
    int g = t >> 6, o = t & 63;
    float sum = bfc[o];
    for (int j = 0; j < HID; j += 4) {
        float4 p = *reinterpret_cast<const float4*>(&pooled[g * HID + j]);
        float4 w = *reinterpret_cast<const float4*>(&Wfc[o * HID + j]);
        sum += p.x * w.x + p.y * w.y + p.z * w.z + p.w * w.w;
    }
    out[t] = sum;
}

extern "C" void kernel_launch(void* const* d_in, const int* in_sizes, int n_in,
                              void* d_out, int out_size, void* d_ws, size_t ws_size,
                              hipStream_t stream)
{
    const float* x     = (const float*)d_in[0];
    const int*   ei    = (const int*)d_in[1];
    const int*   batch = (const int*)d_in[2];
    const float* Win   = (const float*)d_in[3];
    const float* bin_  = (const float*)d_in[4];
    const float* Wq    = (const float*)d_in[5];
    const float* bq    = (const float*)d_in[6];
    const float* Wk    = (const float*)d_in[7];
    const float* bk    = (const float*)d_in[8];
    const float* Wv    = (const float*)d_in[9];
    const float* bv    = (const float*)d_in[10];
    const float* Wskip = (const float*)d_in[11];
    const float* bskip = (const float*)d_in[12];
    const float* Wfc   = (const float*)d_in[13];
    const float* bfc   = (const float*)d_in[14];
    float* out = (float*)d_out;

    // workspace layout (~57 MB), 256B-aligned chunks
    char* ws = (char*)d_ws;
    auto alloc = [&](size_t bytes) {
        void* p = (void*)ws;
        ws += (bytes + 255) & ~(size_t)255;
        return p;
    };
    short* hb     = (short*)alloc((size_t)NN * HID * 2);
    short* qs     = (short*)alloc((size_t)NN * 256 * 2);   // Q(128) + skip(128)
    signed char* kv8 = (signed char*)alloc((size_t)NN * 256); // fp8 K|V interleaved
    short* Wt0    = (short*)alloc((size_t)16384 * 2);      // input Win transposed
    short* Wt     = (short*)alloc((size_t)12 * 16384 * 2); // layer W transposed
    float* bcat   = (float*)alloc((size_t)13 * 128 * 4);
    float* pooled = (float*)alloc((size_t)NG * HID * 4);
    int* deg      = (int*)alloc((size_t)NN * 4);
    int* offsets  = (int*)alloc((size_t)(NN + 1) * 4);
    int* bsum     = (int*)alloc((size_t)64 * 4);
    int* gstart   = (int*)alloc((size_t)(NG + 1) * 4);
    unsigned short* rank16 = (unsigned short*)alloc((size_t)NE * 2);
    unsigned short* csr16  = (unsigned short*)alloc((size_t)NE * 2);

    const int* esrc = ei;
    const int* edst = ei + NE;

    PtrTab wt, bt;
    wt.p[0] = Win; bt.p[0] = bin_;
    for (int l = 0; l < NL; ++l) {
        wt.p[1 + 4 * l] = Wq    + (size_t)l * HID * HID;
        wt.p[2 + 4 * l] = Wk    + (size_t)l * HID * HID;
        wt.p[3 + 4 * l] = Wv    + (size_t)l * HID * HID;
        wt.p[4 + 4 * l] = Wskip + (size_t)l * HID * HID;
        bt.p[1 + 4 * l] = bq    + (size_t)l * HID;
        bt.p[2 + 4 * l] = bk    + (size_t)l * HID;
        bt.p[3 + 4 * l] = bv    + (size_t)l * HID;
        bt.p[4 + 4 * l] = bskip + (size_t)l * HID;
    }

    // zero deg/pooled first (memsets precede preamble on the stream -> no race)
    hipMemsetAsync(deg, 0, (size_t)NN * 4, stream);
    hipMemsetAsync(pooled, 0, (size_t)NG * HID * 4, stream);

    // merged preamble: pack (768 blocks) + count_deg (3125) + gstart (1)
    preamble_kernel<<<PACK_BLOCKS + CD_BLOCKS + 1, 256, 0, stream>>>(
        wt, bt, Wt0, Wt, bcat, edst, deg, rank16, batch, gstart);

    const int nsb = (NN + 1023) / 1024;   // 49
    scan1_kernel<<<nsb, 1024, 0, stream>>>(deg, offsets, bsum, NN);
    scan3_kernel<<<(NN + 255) / 256, 256, 0, stream>>>(offsets, bsum, NN, nsb);
    scatter_kernel<<<(NE + 255) / 256, 256, 0, stream>>>(
        esrc, edst, offsets, rank16, csr16, NE);

    // input projection: h = x @ Win^T + bin (fp32 A converted on load)
    const int gl = (NN + 63) / 64;        // 782
    gemm_in<<<gl, 128, 0, stream>>>(x, Wt0, bcat, hb, NN);

    for (int l = 0; l < NL; ++l) {
        gemm_layer<<<gl, 512, 0, stream>>>(
            hb, Wt + (size_t)l * 16 * 512 * 8, bcat + (1 + 4 * l) * 128, qs, kv8, NN);
        attn_kernel<<<(NN + 3) / 4, 256, 0, stream>>>(qs, kv8, offsets, csr16, hb, NN);
    }

    pool_kernel<<<NG * 8, 256, 0, stream>>>(hb, gstart, pooled);
    fc_kernel<<<16, 256, 0, stream>>>(pooled, Wfc, bfc, out);
}

// Round 16
// 281.831 us; speedup vs baseline: 1.1883x; 1.0053x over previous
//
#include <hip/hip_runtime.h>
#include <math.h>

#define NN 50000
#define NE 800000
#define HID 128
#define NL 3
#define NG 64
#define LAT 64
#define NREP 8   // degree-array replication for atomic spread

typedef __attribute__((ext_vector_type(8))) short short8v;
typedef __attribute__((ext_vector_type(4))) float f32x4;
typedef __attribute__((ext_vector_type(2))) float f32x2;

__device__ __forceinline__ float bf2f(unsigned short b) {
    unsigned u = ((unsigned)b) << 16;
    return __builtin_bit_cast(float, u);
}
__device__ __forceinline__ unsigned short f2bf(float f) {
    unsigned u = __builtin_bit_cast(unsigned, f);
    u += 0x7FFFu + ((u >> 16) & 1u);   // round-to-nearest-even
    return (unsigned short)(u >> 16);
}

// decode 8 fp8 e4m3 (two dwords) against qf[8]: dot product
__device__ __forceinline__ float dot8_fp8(int d0, int d1, const float* qf) {
    f32x2 a01 = __builtin_amdgcn_cvt_pk_f32_fp8(d0, false);
    f32x2 a23 = __builtin_amdgcn_cvt_pk_f32_fp8(d0, true);
    f32x2 a45 = __builtin_amdgcn_cvt_pk_f32_fp8(d1, false);
    f32x2 a67 = __builtin_amdgcn_cvt_pk_f32_fp8(d1, true);
    return a01[0]*qf[0] + a01[1]*qf[1] + a23[0]*qf[2] + a23[1]*qf[3]
         + a45[0]*qf[4] + a45[1]*qf[5] + a67[0]*qf[6] + a67[1]*qf[7];
}
// decode 8 fp8 e4m3 (two dwords), acc += wgt * v
__device__ __forceinline__ void acc8_fp8(int d0, int d1, float wgt, float* acc) {
    f32x2 v01 = __builtin_amdgcn_cvt_pk_f32_fp8(d0, false);
    f32x2 v23 = __builtin_amdgcn_cvt_pk_f32_fp8(d0, true);
    f32x2 v45 = __builtin_amdgcn_cvt_pk_f32_fp8(d1, false);
    f32x2 v67 = __builtin_amdgcn_cvt_pk_f32_fp8(d1, true);
    acc[0] += wgt * v01[0]; acc[1] += wgt * v01[1];
    acc[2] += wgt * v23[0]; acc[3] += wgt * v23[1];
    acc[4] += wgt * v45[0]; acc[5] += wgt * v45[1];
    acc[6] += wgt * v67[0]; acc[7] += wgt * v67[1];
}

struct PtrTab { const float* p[13]; };

// ---------------- merged preamble: pack W + count_deg (8-way rep) + gstart --
#define PACK_BLOCKS 768
#define CD_BLOCKS   ((NE + 255) / 256)
__global__ __launch_bounds__(256) void preamble_kernel(
    PtrTab wt, PtrTab bt, short* __restrict__ Wt0, short* __restrict__ Wt,
    float* __restrict__ bcat,
    const int* __restrict__ edst, int* __restrict__ degR,
    unsigned short* __restrict__ rank16,
    const int* __restrict__ batch, int* __restrict__ gstart)
{
    const int b = blockIdx.x;
    if (b < PACK_BLOCKS) {
        int gid = b * 256 + threadIdx.x;               // covers 12*16384
        if (gid < 16384) {                             // input Win, transposed
            int i  = gid & 7;
            int j  = (gid >> 3) & 127;
            int kb = gid >> 10;
            Wt0[gid] = (short)f2bf(wt.p[0][j * 128 + kb * 8 + i]);
        }
        if (gid < 12 * 16384) {                        // layer W, transposed
            int i  = gid & 7;
            int c  = (gid >> 3) & 511;
            int kb = (gid >> 12) & 15;
            int l  = gid >> 16;
            int slot = 1 + 4 * l + (c >> 7);
            int elem = (c & 127) * 128 + kb * 8 + i;
            Wt[gid] = (short)f2bf(wt.p[slot][elem]);
        }
        if (gid < 13 * 128) {
            int slot = gid >> 7, e = gid & 127;
            bcat[gid] = bt.p[slot][e];
        }
    } else if (b < PACK_BLOCKS + CD_BLOCKS) {
        int cb = b - PACK_BLOCKS;
        int e = cb * 256 + threadIdx.x;
        int r = cb & (NREP - 1);
        if (e < NE) {
            int lr = atomicAdd(&degR[r * NN + edst[e]], 1);
            rank16[e] = (unsigned short)lr;
        }
    } else {
        int t = threadIdx.x;
        if (t <= NG) {
            int lo = 0, hi = NN;
            while (lo < hi) {
                int mid = (lo + hi) >> 1;
                if (batch[mid] < t) lo = mid + 1; else hi = mid;
            }
            gstart[t] = lo;
        }
    }
}

// ---------------- layer GEMM: barrier-free, W direct from L2 (R12-proven) --
__global__ __launch_bounds__(512) void gemm_layer(
    const short* __restrict__ A, const short* __restrict__ Wt_l,
    const float* __restrict__ bias, short* __restrict__ qs,
    signed char* __restrict__ kv8, int nrows)
{
    constexpr int CSTR = 516;
    __shared__ short Clds[16 * CSTR];      // 16.5KB

    const int tid  = threadIdx.x;
    const int lane = tid & 63;
    const int wid  = tid >> 6;             // 0..7 -> col group
    const int n0   = wid * 64;
    const int lg   = lane >> 4;
    const int l15  = lane & 15;
    const int rb   = blockIdx.x * 64;
    const int r0   = rb + l15;

    f32x4 acc[4][4];
#pragma unroll
    for (int i = 0; i < 4; ++i)
#pragma unroll
        for (int j = 0; j < 4; ++j) acc[i][j] = {0.f, 0.f, 0.f, 0.f};

    const short8v zero8 = {0, 0, 0, 0, 0, 0, 0, 0};

#pragma unroll
    for (int s = 0; s < 4; ++s) {
        short8v a[4], b[4];
#pragma unroll
        for (int mf = 0; mf < 4; ++mf) {
            int row = r0 + mf * 16;
            a[mf] = (row < nrows)
                ? *reinterpret_cast<const short8v*>(&A[(size_t)row * HID + s * 32 + lg * 8])
                : zero8;
        }
        const int kb = s * 4 + lg;
#pragma unroll
        for (int nf = 0; nf < 4; ++nf) {
            int col = n0 + nf * 16 + l15;
            b[nf] = *reinterpret_cast<const short8v*>(&Wt_l[((size_t)kb * 512 + col) * 8]);
        }
#pragma unroll
        for (int mf = 0; mf < 4; ++mf)
#pragma unroll
            for (int nf = 0; nf < 4; ++nf)
                acc[mf][nf] = __builtin_amdgcn_mfma_f32_16x16x32_bf16(
                    a[mf], b[nf], acc[mf][nf], 0, 0, 0);
    }

    // ---- epilogue: 4 passes of 16 rows through LDS ----
#pragma unroll
    for (int mf = 0; mf < 4; ++mf) {
        __syncthreads();
#pragma unroll
        for (int nf = 0; nf < 4; ++nf) {
            int col = n0 + nf * 16 + l15;
            float bv = bias[col];
#pragma unroll
            for (int qq = 0; qq < 4; ++qq) {
                int rl = lg * 4 + qq;              // 0..15
                Clds[rl * CSTR + col] = (short)f2bf(acc[mf][nf][qq] + bv);
            }
        }
        __syncthreads();
#pragma unroll
        for (int i = 0; i < 2; ++i) {              // 16 rows * 64 chunks / 512
            int c = tid + 512 * i;
            int rl = c >> 6;
            int ck = c & 63;
            int grow = rb + mf * 16 + rl;
            if (grow < nrows) {
                if (ck < 16) {                     // Q -> qs (stride 256)
                    *reinterpret_cast<short8v*>(&qs[(size_t)grow * 256 + ck * 8]) =
                        *reinterpret_cast<const short8v*>(&Clds[rl * CSTR + ck * 8]);
                } else if (ck < 48) {              // K/V -> fp8 interleaved
                    short8v cv = *reinterpret_cast<const short8v*>(&Clds[rl * CSTR + ck * 8]);
                    float f0 = bf2f((unsigned short)cv[0]), f1 = bf2f((unsigned short)cv[1]);
                    float f2 = bf2f((unsigned short)cv[2]), f3 = bf2f((unsigned short)cv[3]);
                    float f4 = bf2f((unsigned short)cv[4]), f5 = bf2f((unsigned short)cv[5]);
                    float f6 = bf2f((unsigned short)cv[6]), f7 = bf2f((unsigned short)cv[7]);
                    int w0 = __builtin_amdgcn_cvt_pk_fp8_f32(f0, f1, 0, false);
                    w0     = __builtin_amdgcn_cvt_pk_fp8_f32(f2, f3, w0, true);
                    int w1 = __builtin_amdgcn_cvt_pk_fp8_f32(f4, f5, 0, false);
                    w1     = __builtin_amdgcn_cvt_pk_fp8_f32(f6, f7, w1, true);
                    int off = (ck < 32) ? (ck - 16) * 16 : ((ck - 32) * 16 + 8);
                    *reinterpret_cast<int2*>(kv8 + (size_t)grow * 256 + off) =
                        make_int2(w0, w1);
                } else {                           // skip -> qs at +128
                    *reinterpret_cast<short8v*>(&qs[(size_t)grow * 256 + 128 + (ck - 48) * 8]) =
                        *reinterpret_cast<const short8v*>(&Clds[rl * CSTR + ck * 8]);
                }
            }
        }
    }
}

// ---------------- input GEMM: barrier-free, W direct from L2 ---------------
__global__ __launch_bounds__(128) void gemm_in(
    const float* __restrict__ Af, const short* __restrict__ Wt0,
    const float* __restrict__ bias, short* __restrict__ out, int nrows)
{
    constexpr int CSTR = 132;
    __shared__ short Clds[16 * CSTR];      // 4.2KB

    const int tid  = threadIdx.x;
    const int lane = tid & 63;
    const int wid  = tid >> 6;             // 0..1 -> col half
    const int n0   = wid * 64;
    const int lg   = lane >> 4;
    const int l15  = lane & 15;
    const int rb   = blockIdx.x * 64;
    const int r0   = rb + l15;

    f32x4 acc[4][4];
#pragma unroll
    for (int i = 0; i < 4; ++i)
#pragma unroll
        for (int j = 0; j < 4; ++j) acc[i][j] = {0.f, 0.f, 0.f, 0.f};

    const short8v zero8 = {0, 0, 0, 0, 0, 0, 0, 0};

#pragma unroll
    for (int s = 0; s < 4; ++s) {
        short8v a[4], b[4];
#pragma unroll
        for (int mf = 0; mf < 4; ++mf) {
            int row = r0 + mf * 16;
            if (row < nrows) {
                const float* ap = Af + (size_t)row * HID + s * 32 + lg * 8;
                float4 f0 = *reinterpret_cast<const float4*>(ap);
                float4 f1 = *reinterpret_cast<const float4*>(ap + 4);
                short8v t;
                t[0] = (short)f2bf(f0.x); t[1] = (short)f2bf(f0.y);
                t[2] = (short)f2bf(f0.z); t[3] = (short)f2bf(f0.w);
                t[4] = (short)f2bf(f1.x); t[5] = (short)f2bf(f1.y);
                t[6] = (short)f2bf(f1.z); t[7] = (short)f2bf(f1.w);
                a[mf] = t;
            } else a[mf] = zero8;
        }
        const int kb = s * 4 + lg;
#pragma unroll
        for (int nf = 0; nf < 4; ++nf) {
            int col = n0 + nf * 16 + l15;
            b[nf] = *reinterpret_cast<const short8v*>(&Wt0[((size_t)kb * 128 + col) * 8]);
        }
#pragma unroll
        for (int mf = 0; mf < 4; ++mf)
#pragma unroll
            for (int nf = 0; nf < 4; ++nf)
                acc[mf][nf] = __builtin_amdgcn_mfma_f32_16x16x32_bf16(
                    a[mf], b[nf], acc[mf][nf], 0, 0, 0);
    }

#pragma unroll
    for (int mf = 0; mf < 4; ++mf) {
        __syncthreads();
#pragma unroll
        for (int nf = 0; nf < 4; ++nf) {
            int col = n0 + nf * 16 + l15;
            float bv = bias[col];
#pragma unroll
            for (int qq = 0; qq < 4; ++qq) {
                int rl = lg * 4 + qq;              // 0..15
                Clds[rl * CSTR + col] = (short)f2bf(acc[mf][nf][qq] + bv);
            }
        }
        __syncthreads();
#pragma unroll
        for (int i = 0; i < 2; ++i) {              // 16 rows * 16 chunks / 128
            int c = tid + 128 * i;
            int rl = c >> 4;
            int ck = c & 15;
            int grow = rb + mf * 16 + rl;
            if (grow < nrows)
                *reinterpret_cast<short8v*>(&out[(size_t)grow * HID + ck * 8]) =
                    *reinterpret_cast<const short8v*>(&Clds[rl * CSTR + ck * 8]);
        }
    }
}

// ---------------- scans + scatter ----------------
// scan1: total deg = sum of 8 replicas
__global__ __launch_bounds__(1024) void scan1_kernel(
    const int* __restrict__ degR, int* __restrict__ offsets,
    int* __restrict__ bsum, int n)
{
    __shared__ int wsum[16];
    const int tid = threadIdx.x, wid = tid >> 6, lane = tid & 63;
    int i = blockIdx.x * 1024 + tid;
    int val = 0;
    if (i < n) {
#pragma unroll
        for (int r = 0; r < NREP; ++r) val += degR[r * NN + i];
    }
    int x = val;
#pragma unroll
    for (int off = 1; off < 64; off <<= 1) {
        int y = __shfl_up(x, off);
        if (lane >= off) x += y;
    }
    if (lane == 63) wsum[wid] = x;
    __syncthreads();
    if (tid < 16) {
        int w = wsum[tid];
#pragma unroll
        for (int off = 1; off < 16; off <<= 1) {
            int y = __shfl_up(w, off);
            if (tid >= off) w += y;
        }
        wsum[tid] = w;
    }
    __syncthreads();
    int incl = x + (wid ? wsum[wid - 1] : 0);
    if (i < n) offsets[i + 1] = incl;
    if (tid == 1023) bsum[blockIdx.x] = incl;
}

// scan3: finalize offsets; emit per-replica segment starts offsetsR[r][i]
__global__ __launch_bounds__(256) void scan3_kernel(
    int* __restrict__ offsets, const int* __restrict__ bsum,
    const int* __restrict__ degR, int* __restrict__ offsetsR, int n, int nb)
{
    __shared__ int sx[64];
    const int tid = threadIdx.x;
    if (tid < 64) {
        int vv = (tid < nb) ? bsum[tid] : 0;
        int x = vv;
#pragma unroll
        for (int off = 1; off < 64; off <<= 1) {
            int y = __shfl_up(x, off);
            if (tid >= off) x += y;
        }
        sx[tid] = x - vv;   // exclusive prefix of block sums
    }
    __syncthreads();
    int i = blockIdx.x * 256 + tid;
    if (i >= n) return;
    int dr[NREP];
    int tot = 0;
#pragma unroll
    for (int r = 0; r < NREP; ++r) { dr[r] = degR[r * NN + i]; tot += dr[r]; }
    int incl = offsets[i + 1] + sx[i >> 10];
    offsets[i + 1] = incl;
    if (i == 0) offsets[0] = 0;
    int run = incl - tot;                 // segment start for node i
#pragma unroll
    for (int r = 0; r < NREP; ++r) {
        offsetsR[r * NN + i] = run;
        run += dr[r];
    }
}

__global__ __launch_bounds__(256) void scatter_kernel(
    const int* __restrict__ src, const int* __restrict__ dst,
    const int* __restrict__ offsetsR, const unsigned short* __restrict__ rank16,
    unsigned short* __restrict__ csr16, int ne)
{
    int e = blockIdx.x * 256 + threadIdx.x;
    if (e < ne) {
        int r = (e >> 8) & (NREP - 1);    // matches preamble's cb & 7
        int pos = offsetsR[r * NN + dst[e]] + rank16[e];
        csr16[pos] = (unsigned short)src[e];
    }
}

// ---------------- fused attention + skip + ReLU ----------------
__global__ __launch_bounds__(256) void attn_kernel(
    const short* __restrict__ qs, const signed char* __restrict__ kv8,
    const int* __restrict__ offsets, const unsigned short* __restrict__ csr16,
    short* __restrict__ hout, int nnodes)
{
    int node = (blockIdx.x * 256 + threadIdx.x) >> 6;
    if (node >= nnodes) return;
    const int lane = threadIdx.x & 63;
    const int grp = lane >> 4;        // edge slot 0..3
    const int g   = lane & 15;        // dims 8g..8g+7 (head = g/4)
    const float scale = 0.17677669529663687f; // 1/sqrt(32)

    const size_t nb = (size_t)node * 256;
    short8v q8 = *reinterpret_cast<const short8v*>(&qs[nb + g * 8]);
    float qf[8];
#pragma unroll
    for (int i = 0; i < 8; ++i) qf[i] = bf2f((unsigned short)q8[i]);

    int e0 = offsets[node], e1 = offsets[node + 1];
    float s = 0.f;
    float acc[8] = {0.f, 0.f, 0.f, 0.f, 0.f, 0.f, 0.f, 0.f};

    const signed char* kvb = kv8 + g * 16;

    int e = e0 + grp;
    int i0 = (e < e1)     ? (int)csr16[e]     : 0;
    int i1 = (e + 4 < e1) ? (int)csr16[e + 4] : 0;

    for (; e + 4 < e1; e += 8) {
        int j0 = (e + 8  < e1) ? (int)csr16[e + 8]  : 0;   // prefetch next pair
        int j1 = (e + 12 < e1) ? (int)csr16[e + 12] : 0;
        int4 kv0 = *reinterpret_cast<const int4*>(kvb + ((size_t)i0 << 8));
        int4 kv1 = *reinterpret_cast<const int4*>(kvb + ((size_t)i1 << 8));
        float p0 = dot8_fp8(kv0.x, kv0.y, qf);
        float p1 = dot8_fp8(kv1.x, kv1.y, qf);
        p0 += __shfl_xor(p0, 1);  p1 += __shfl_xor(p1, 1);
        p0 += __shfl_xor(p0, 2);  p1 += __shfl_xor(p1, 2);
        float w0 = __expf(fminf(p0 * scale, 60.f));
        float w1 = __expf(fminf(p1 * scale, 60.f));
        s += w0 + w1;
        acc8_fp8(kv0.z, kv0.w, w0, acc);
        acc8_fp8(kv1.z, kv1.w, w1, acc);
        i0 = j0; i1 = j1;
    }
    if (e < e1) {
        int4 kv0 = *reinterpret_cast<const int4*>(kvb + ((size_t)i0 << 8));
        float p0 = dot8_fp8(kv0.x, kv0.y, qf);
        p0 += __shfl_xor(p0, 1);
        p0 += __shfl_xor(p0, 2);
        float w0 = __expf(fminf(p0 * scale, 60.f));
        s += w0;
        acc8_fp8(kv0.z, kv0.w, w0, acc);
    }

    // merge the 4 edge slots (once per node)
#pragma unroll
    for (int off = 16; off <= 32; off <<= 1) {
        s += __shfl_xor(s, off);
#pragma unroll
        for (int i = 0; i < 8; ++i) acc[i] += __shfl_xor(acc[i], off);
    }
    float inv = 1.f / (s + 1e-16f);
    short8v sk8 = *reinterpret_cast<const short8v*>(&qs[nb + 128 + g * 8]);
    short8v o;
#pragma unroll
    for (int i = 0; i < 8; ++i) {
        float ov = fmaxf(acc[i] * inv + bf2f((unsigned short)sk8[i]), 0.f);
        o[i] = (short)f2bf(ov);
    }
    *reinterpret_cast<short8v*>(&hout[(size_t)node * HID + g * 8]) = o;
}

// ---------------- pooling: block per (graph, row-chunk), LDS reduce --------
__global__ __launch_bounds__(256) void pool_kernel(
    const short* __restrict__ h, const int* __restrict__ gstart,
    float* __restrict__ pooled)
{
    __shared__ float sdata[16][HID];
    const int g  = blockIdx.x >> 3;        // graph
    const int rc = blockIdx.x & 7;         // row chunk
    const int rg = threadIdx.x >> 4;       // 16 row streams
    const int c8 = threadIdx.x & 15;       // 8 cols each
    const int n0 = gstart[g], n1 = gstart[g + 1];

    float s[8] = {0.f, 0.f, 0.f, 0.f, 0.f, 0.f, 0.f, 0.f};
    for (int n = n0 + rc * 16 + rg; n < n1; n += 128) {
        short8v hv = *reinterpret_cast<const short8v*>(&h[(size_t)n * HID + c8 * 8]);
#pragma unroll
        for (int i = 0; i < 8; ++i) s[i] += bf2f((unsigned short)hv[i]);
    }
#pragma unroll
    for (int i = 0; i < 8; ++i) sdata[rg][c8 * 8 + i] = s[i];
    __syncthreads();
    if (threadIdx.x < HID) {
        float sum = 0.f;
#pragma unroll
        for (int r = 0; r < 16; ++r) sum += sdata[r][threadIdx.x];
        atomicAdd(&pooled[g * HID + threadIdx.x], sum);
    }
}

// ---------------- final FC ----------------
__global__ __launch_bounds__(256) void fc_kernel(
    const float* __restrict__ pooled, const float* __restrict__ Wfc,
    const float* __restrict__ bfc, float* __restrict__ out)
{
    int t = blockIdx.x * 256 + threadIdx.x;   // 4096 = G*LAT
    if (t >= NG * LAT) return;
    int g = t >> 6, o = t & 63;
    float sum = bfc[o];
    for (int j = 0; j < HID; j += 4) {
        float4 p = *reinterpret_cast<const float4*>(&pooled[g * HID + j]);
        float4 w = *reinterpret_cast<const float4*>(&Wfc[o * HID + j]);
        sum += p.x * w.x + p.y * w.y + p.z * w.z + p.w * w.w;
    }
    out[t] = sum;
}

extern "C" void kernel_launch(void* const* d_in, const int* in_sizes, int n_in,
                              void* d_out, int out_size, void* d_ws, size_t ws_size,
                              hipStream_t stream)
{
    const float* x     = (const float*)d_in[0];
    const int*   ei    = (const int*)d_in[1];
    const int*   batch = (const int*)d_in[2];
    const float* Win   = (const float*)d_in[3];
    const float* bin_  = (const float*)d_in[4];
    const float* Wq    = (const float*)d_in[5];
    const float* bq    = (const float*)d_in[6];
    const float* Wk    = (const float*)d_in[7];
    const float* bk    = (const float*)d_in[8];
    const float* Wv    = (const float*)d_in[9];
    const float* bv    = (const float*)d_in[10];
    const float* Wskip = (const float*)d_in[11];
    const float* bskip = (const float*)d_in[12];
    const float* Wfc   = (const float*)d_in[13];
    const float* bfc   = (const float*)d_in[14];
    float* out = (float*)d_out;

    // workspace layout (~60 MB), 256B-aligned chunks
    char* ws = (char*)d_ws;
    auto alloc = [&](size_t bytes) {
        void* p = (void*)ws;
        ws += (bytes + 255) & ~(size_t)255;
        return p;
    };
    short* hb     = (short*)alloc((size_t)NN * HID * 2);
    short* qs     = (short*)alloc((size_t)NN * 256 * 2);   // Q(128) + skip(128)
    signed char* kv8 = (signed char*)alloc((size_t)NN * 256); // fp8 K|V interleaved
    short* Wt0    = (short*)alloc((size_t)16384 * 2);      // input Win transposed
    short* Wt     = (short*)alloc((size_t)12 * 16384 * 2); // layer W transposed
    float* bcat   = (float*)alloc((size_t)13 * 128 * 4);
    float* pooled = (float*)alloc((size_t)NG * HID * 4);
    int* degR     = (int*)alloc((size_t)NREP * NN * 4);    // 8-way replicated deg
    int* offsets  = (int*)alloc((size_t)(NN + 1) * 4);
    int* offsetsR = (int*)alloc((size_t)NREP * NN * 4);    // per-replica starts
    int* bsum     = (int*)alloc((size_t)64 * 4);
    int* gstart   = (int*)alloc((size_t)(NG + 1) * 4);
    unsigned short* rank16 = (unsigned short*)alloc((size_t)NE * 2);
    unsigned short* csr16  = (unsigned short*)alloc((size_t)NE * 2);

    const int* esrc = ei;
    const int* edst = ei + NE;

    PtrTab wt, bt;
    wt.p[0] = Win; bt.p[0] = bin_;
    for (int l = 0; l < NL; ++l) {
        wt.p[1 + 4 * l] = Wq    + (size_t)l * HID * HID;
        wt.p[2 + 4 * l] = Wk    + (size_t)l * HID * HID;
        wt.p[3 + 4 * l] = Wv    + (size_t)l * HID * HID;
        wt.p[4 + 4 * l] = Wskip + (size_t)l * HID * HID;
        bt.p[1 + 4 * l] = bq    + (size_t)l * HID;
        bt.p[2 + 4 * l] = bk    + (size_t)l * HID;
        bt.p[3 + 4 * l] = bv    + (size_t)l * HID;
        bt.p[4 + 4 * l] = bskip + (size_t)l * HID;
    }

    // zero degR/pooled first (memsets precede preamble on the stream -> no race)
    hipMemsetAsync(degR, 0, (size_t)NREP * NN * 4, stream);
    hipMemsetAsync(pooled, 0, (size_t)NG * HID * 4, stream);

    // merged preamble: pack (768 blocks) + count_deg (3125, 8-way) + gstart (1)
    preamble_kernel<<<PACK_BLOCKS + CD_BLOCKS + 1, 256, 0, stream>>>(
        wt, bt, Wt0, Wt, bcat, edst, degR, rank16, batch, gstart);

    const int nsb = (NN + 1023) / 1024;   // 49
    scan1_kernel<<<nsb, 1024, 0, stream>>>(degR, offsets, bsum, NN);
    scan3_kernel<<<(NN + 255) / 256, 256, 0, stream>>>(
        offsets, bsum, degR, offsetsR, NN, nsb);
    scatter_kernel<<<(NE + 255) / 256, 256, 0, stream>>>(
        esrc, edst, offsetsR, rank16, csr16, NE);

    // input projection: h = x @ Win^T + bin (fp32 A converted on load)
    const int gl = (NN + 63) / 64;        // 782
    gemm_in<<<gl, 128, 0, stream>>>(x, Wt0, bcat, hb, NN);

    for (int l = 0; l < NL; ++l) {
        gemm_layer<<<gl, 512, 0, stream>>>(
            hb, Wt + (size_t)l * 16 * 512 * 8, bcat + (1 + 4 * l) * 128, qs, kv8, NN);
        attn_kernel<<<(NN + 3) / 4, 256, 0, stream>>>(qs, kv8, offsets, csr16, hb, NN);
    }

    pool_kernel<<<NG * 8, 256, 0, stream>>>(hb, gstart, pooled);
    fc_kernel<<<16, 256, 0, stream>>>(pooled, Wfc, bfc, out);
}